// Round 1
// baseline (659.247 us; speedup 1.0000x reference)
//
#include <hip/hip_runtime.h>
#include <hip/hip_bf16.h>

typedef __bf16 bf16_t;
typedef __bf16 bf16x8 __attribute__((ext_vector_type(8)));
typedef float f32x4 __attribute__((ext_vector_type(4)));

#define B_DIM 8
#define LQ 1024
#define LK 1024
#define DD 512
#define NH 8
#define LB 2          // batches per chunk
#define NCH 4         // chunks

static __device__ __forceinline__ f32x4 mfma_bf16(bf16x8 a, bf16x8 b, f32x4 c) {
  return __builtin_amdgcn_mfma_f32_16x16x32_bf16(a, b, c, 0, 0, 0);
}

// async global->LDS, 16B per lane (wave-uniform LDS base + lane*16)
static __device__ __forceinline__ void gld_lds16(const bf16_t* g, bf16_t* l) {
  __builtin_amdgcn_global_load_lds(
      (const __attribute__((address_space(1))) void*)g,
      (__attribute__((address_space(3))) void*)l, 16, 0, 0);
}

// ---------------- fp32 -> bf16 conversions ----------------
__global__ void cvt_pair(const float* __restrict__ s0, bf16_t* __restrict__ d0,
                         const float* __restrict__ s1, bf16_t* __restrict__ d1, int n) {
  const float* s = blockIdx.y ? s1 : s0;
  bf16_t* d = blockIdx.y ? d1 : d0;
  int i = (blockIdx.x * 256 + threadIdx.x) * 4;
  if (i < n) {
    const float4 f = *(const float4*)(s + i);
    bf16_t* p = d + i;
    p[0] = (bf16_t)f.x; p[1] = (bf16_t)f.y; p[2] = (bf16_t)f.z; p[3] = (bf16_t)f.w;
  }
}

__global__ void cvt_w3(const float* __restrict__ s0, const float* __restrict__ s1,
                       const float* __restrict__ s2, bf16_t* __restrict__ d0,
                       bf16_t* __restrict__ d1, bf16_t* __restrict__ d2, int n) {
  const float* s = (blockIdx.y == 0) ? s0 : (blockIdx.y == 1) ? s1 : s2;
  bf16_t* d = (blockIdx.y == 0) ? d0 : (blockIdx.y == 1) ? d1 : d2;
  int i = (blockIdx.x * 256 + threadIdx.x) * 4;
  if (i < n) {
    const float4 f = *(const float4*)(s + i);
    bf16_t* p = d + i;
    p[0] = (bf16_t)f.x; p[1] = (bf16_t)f.y; p[2] = (bf16_t)f.z; p[3] = (bf16_t)f.w;
  }
}

__global__ void cvt_f32_bf16(const float* __restrict__ s, bf16_t* __restrict__ d, int n) {
  int i = (blockIdx.x * 256 + threadIdx.x) * 4;
  if (i < n) {
    const float4 f = *(const float4*)(s + i);
    bf16_t* p = d + i;
    p[0] = (bf16_t)f.x; p[1] = (bf16_t)f.y; p[2] = (bf16_t)f.z; p[3] = (bf16_t)f.w;
  }
}

// ======================================================================
// OLD 128x128 / BK=64 core (kept for gemm_pv, whose 256^2 grid would be
// only 128 blocks = half the CUs).
// ======================================================================
static __device__ __forceinline__ void gemm_core(
    const bf16_t* __restrict__ A, const bf16_t* __restrict__ B, int ld, int klen,
    int m0, int n0, bf16_t* As, bf16_t* Bs, f32x4 (&acc)[4][4])
{
  const int tid = threadIdx.x;
  const int wave = tid >> 6, lane = tid & 63;
  const int l15 = lane & 15, quad = lane >> 4;
  const int wm = (wave & 1) * 64, wn = (wave >> 1) * 64;

  const int r0 = tid >> 3;        // + p*32 per pass
  const int c8s = tid & 7;        // stored chunk index
  bf16_t* Asl = As + tid * 8;
  bf16_t* Bsl = Bs + tid * 8;

  for (int k0 = 0; k0 < klen; k0 += 64) {
    __syncthreads();
#pragma unroll
    for (int p = 0; p < 4; ++p) {
      const int r = r0 + p * 32;
      const int gc = ((c8s ^ (r & 7)) * 8) + k0;
      gld_lds16(A + (size_t)(m0 + r) * ld + gc, Asl + p * 2048);
      gld_lds16(B + (size_t)(n0 + r) * ld + gc, Bsl + p * 2048);
    }
    __syncthreads();  // drains vmcnt
#pragma unroll
    for (int ks = 0; ks < 2; ++ks) {
      bf16x8 af[4], bfr[4];
#pragma unroll
      for (int i = 0; i < 4; ++i) {
        const int r = wm + i * 16 + l15;
        af[i] = *(const bf16x8*)&As[(r * 8 + ((ks * 4 + quad) ^ (r & 7))) * 8];
      }
#pragma unroll
      for (int j = 0; j < 4; ++j) {
        const int r = wn + j * 16 + l15;
        bfr[j] = *(const bf16x8*)&Bs[(r * 8 + ((ks * 4 + quad) ^ (r & 7))) * 8];
      }
#pragma unroll
      for (int i = 0; i < 4; ++i)
#pragma unroll
        for (int j = 0; j < 4; ++j)
          acc[i][j] = mfma_bf16(af[i], bfr[j], acc[i][j]);
    }
  }
}

// ======================================================================
// NEW 256x256 / BK=64 / 8-wave / 8-phase core (T3+T4+T5 per m194-m201).
//
// Geometry: 512 thr = 8 waves (2M x 4N). Wave tile 128x64, frags
// interleaved: m-frag i at block-row (i>>2)*128 + wm*16 + (i&3)*32,
// n-frag j at block-col (j>>1)*128 + wn*16 + (j&1)*64  -> quadrant
// (mh,nh) of every wave reads exactly block A-half mh / B-half nh.
//
// LDS: per matrix 2 dbuf slots x 2 halves x [128 rows x 64 cols] with the
// proven XOR-chunk scheme (slot s holds row s>>3, global chunk (s&7)^(r&7);
// 2-way-max bank aliasing = free, measured 0 conflicts).  64 KiB A + 64 KiB
// B = 128 KiB -> 1 block/CU.
//
// Phase schedule per K-tile kt (4 phases, quadrants (m0n0)(m1n0)(m0n1)(m1n1)):
//   P0: ds_read A-half0(8)+B-half0(4)            | MFMA Q(0,0)
//   P1: ds_read A-half1(8); stage kt+2 A0,B0     | MFMA Q(1,0)
//   P2: ds_read B-half1(4); stage kt+2 A1        | MFMA Q(0,1)
//   P3:                    stage kt+2 B1         | MFMA Q(1,1)
// Race-safety: region R of slot kt&1 is LDS-read in exactly one phase
// (A0,B0 in P0; A1 in P1; B1 in P2), and its kt+2 overwrite is issued one
// phase later, i.e. after the trailing s_barrier that proves all waves'
// reads of R landed (lgkmcnt(0) precedes that barrier).  kt+1 stages write
// the opposite slot (always safe).  End-of-ktile s_waitcnt vmcnt(8) (= the
// 8 kt+2 loads still allowed in flight) BEFORE the trailing barrier proves
// kt+1 fully landed to all waves.  Never vmcnt(0) in steady state.
// ======================================================================
#define SBAR() __builtin_amdgcn_s_barrier()
#define SETPRIO(x) __builtin_amdgcn_s_setprio(x)
#define LGKM0() do { asm volatile("s_waitcnt lgkmcnt(0)" ::: "memory"); \
                     __builtin_amdgcn_sched_barrier(0); } while (0)
#define VMC(n) asm volatile("s_waitcnt vmcnt(" #n ")" ::: "memory")

static __device__ __forceinline__ void gemm256_core(
    const bf16_t* __restrict__ A, const bf16_t* __restrict__ Bm,
    const int ld, const int nkt, const int m0, const int n0,
    bf16_t* __restrict__ As, bf16_t* __restrict__ Bs, f32x4 (&acc)[8][4])
{
  const int tid = threadIdx.x;
  const int wave = tid >> 6, lane = tid & 63;
  const int l15 = lane & 15, quad = lane >> 4;
  const int wm = ((wave >> 2) & 1) << 4;   // 0 / 16
  const int wn = (wave & 3) << 4;          // 0 / 16 / 32 / 48

  // staging: 1024 slots per 128x64 half-tile, 512 threads x 2 passes
  const int s1 = tid + 512;
  const int r0 = tid >> 3, r1 = s1 >> 3;
  const int g0 = ((tid & 7) ^ (r0 & 7)) << 3;
  const int g1 = ((s1 & 7) ^ (r1 & 7)) << 3;
  const bf16_t* pa0 = A + (size_t)(m0 + r0) * ld + g0;
  const bf16_t* pa1 = A + (size_t)(m0 + r1) * ld + g1;
  const bf16_t* pb0 = Bm + (size_t)(n0 + r0) * ld + g0;
  const bf16_t* pb1 = Bm + (size_t)(n0 + r1) * ld + g1;
  const size_t hgl = (size_t)128 * ld;     // global step per 128-row half
  bf16_t* la = As + tid * 8;
  bf16_t* lb = Bs + tid * 8;

#define STG_A(kt, h) do { const int _o = (((kt) & 1) << 14) + ((h) << 13); \
    const size_t _g = (size_t)(h) * hgl + ((kt) << 6); \
    gld_lds16(pa0 + _g, la + _o); gld_lds16(pa1 + _g, la + _o + 4096); } while (0)
#define STG_B(kt, h) do { const int _o = (((kt) & 1) << 14) + ((h) << 13); \
    const size_t _g = (size_t)(h) * hgl + ((kt) << 6); \
    gld_lds16(pb0 + _g, lb + _o); gld_lds16(pb1 + _g, lb + _o + 4096); } while (0)

  bf16x8 af[2][4][2];   // [mh][a][ks]  A frags, both halves live per K-tile
  bf16x8 bfrag[2][2];   // [b][ks]      B frags, current n-half only

#define RD_A(mh) do { _Pragma("unroll") for (int a = 0; a < 4; ++a) { \
    const int rl = wm + a * 32 + l15; \
    const int rb = sb + ((mh) << 13) + rl * 64; \
    _Pragma("unroll") for (int ks = 0; ks < 2; ++ks) \
      af[mh][a][ks] = *(const bf16x8*)&As[rb + (((ks * 4 + quad) ^ (rl & 7)) << 3)]; \
  } } while (0)
#define RD_B(nh) do { _Pragma("unroll") for (int b = 0; b < 2; ++b) { \
    const int rl = wn + b * 64 + l15; \
    const int rb = sb + ((nh) << 13) + rl * 64; \
    _Pragma("unroll") for (int ks = 0; ks < 2; ++ks) \
      bfrag[b][ks] = *(const bf16x8*)&Bs[rb + (((ks * 4 + quad) ^ (rl & 7)) << 3)]; \
  } } while (0)
#define MMA(mh, nh) do { _Pragma("unroll") for (int ks = 0; ks < 2; ++ks) \
    _Pragma("unroll") for (int a = 0; a < 4; ++a) \
    _Pragma("unroll") for (int b = 0; b < 2; ++b) \
      acc[(mh) * 4 + a][(nh) * 2 + b] = \
          mfma_bf16(af[mh][a][ks], bfrag[b][ks], acc[(mh) * 4 + a][(nh) * 2 + b]); \
  } while (0)

  // prologue: stage kt0 and kt1 fully (16 loads); wait oldest 8 (= kt0)
  STG_A(0, 0); STG_A(0, 1); STG_B(0, 0); STG_B(0, 1);
  if (nkt > 1) {
    STG_A(1, 0); STG_A(1, 1); STG_B(1, 0); STG_B(1, 1);
    VMC(8);
  } else {
    VMC(0);
  }
  SBAR();

#pragma unroll 2
  for (int kt = 0; kt < nkt; ++kt) {
    const int sb = (kt & 1) << 14;
    const int kt2 = kt + 2;
    const bool pf = kt2 < nkt;
    // ---- P0: quadrant (m0,n0)
    RD_A(0); RD_B(0);
    SBAR(); LGKM0();
    SETPRIO(1); MMA(0, 0); SETPRIO(0);
    SBAR();
    // ---- P1: quadrant (m1,n0); prefetch kt+2 A0,B0 (regions last read in P0)
    RD_A(1);
    if (pf) { STG_A(kt2, 0); STG_B(kt2, 0); }
    SBAR(); LGKM0();
    SETPRIO(1); MMA(1, 0); SETPRIO(0);
    SBAR();
    // ---- P2: quadrant (m0,n1); prefetch kt+2 A1 (region last read in P1)
    RD_B(1);
    if (pf) STG_A(kt2, 1);
    SBAR(); LGKM0();
    SETPRIO(1); MMA(0, 1); SETPRIO(0);
    SBAR();
    // ---- P3: quadrant (m1,n1); prefetch kt+2 B1 (region last read in P2)
    if (pf) STG_B(kt2, 1);
    SBAR(); LGKM0();
    SETPRIO(1); MMA(1, 1); SETPRIO(0);
    if (kt < nkt - 1) {
      if (pf) { VMC(8); } else { VMC(0); }  // prove kt+1 landed, keep kt+2 in flight
      SBAR();
    }
  }
#undef STG_A
#undef STG_B
#undef RD_A
#undef RD_B
#undef MMA
}

// C row/col for acc[i][j] reg r (dtype-independent C/D map: col=l15, row=quad*4+r)
#define ROW256(i, r) (m0 + (((i) >> 2) << 7) + wm + ((i) & 3) * 32 + quad * 4 + (r))
#define COL256(j)    (n0 + (((j) >> 1) << 7) + wn + ((j) & 1) * 64 + l15)

// ---------------- fused Q/K/Vt projections (256^2 8-phase) ----------------
// grid (8, 3*LB*NH).  blockIdx.y = role*16 + z, z = bb*NH+hh.
__global__ __launch_bounds__(512, 2) void gemm_qkv(
    const bf16_t* __restrict__ xcb, const bf16_t* __restrict__ scb,
    const bf16_t* __restrict__ wq, const bf16_t* __restrict__ wk,
    const bf16_t* __restrict__ wv,
    const float* __restrict__ bq, const float* __restrict__ bk,
    const float* __restrict__ bv,
    bf16_t* __restrict__ Qc, bf16_t* __restrict__ Kc, bf16_t* __restrict__ Vtc)
{
  const int role = blockIdx.y >> 4, z = blockIdx.y & 15;
  const int bb = z >> 3, hh = z & 7;
  const int tx = blockIdx.x;

  const bf16_t* A; const bf16_t* Bm; const float* bias; bf16_t* C;
  int m0, n0, ldc, bias_row;
  if (role == 0) {
    A = xcb + (size_t)bb * LQ * DD; Bm = wq + (size_t)hh * DD * DD;
    bias = bq + hh * DD; C = Qc + (size_t)z * LQ * DD;
    m0 = (tx >> 1) * 256; n0 = (tx & 1) * 256; ldc = DD; bias_row = 0;
  } else if (role == 1) {
    A = scb + (size_t)bb * LK * DD; Bm = wk + (size_t)hh * DD * DD;
    bias = bk + hh * DD; C = Kc + (size_t)z * LK * DD;
    m0 = (tx >> 1) * 256; n0 = (tx & 1) * 256; ldc = DD; bias_row = 0;
  } else {
    A = wv + (size_t)hh * DD * DD; Bm = scb + (size_t)bb * LK * DD;
    bias = bv + hh * DD; C = Vtc + (size_t)z * DD * LK;
    m0 = (tx & 1) * 256; n0 = (tx >> 1) * 256; ldc = LK; bias_row = 1;
  }

  __shared__ __align__(16) bf16_t As[32768];   // 64 KiB
  __shared__ __align__(16) bf16_t Bs[32768];   // 64 KiB
  f32x4 acc[8][4];
#pragma unroll
  for (int i = 0; i < 8; ++i)
#pragma unroll
    for (int j = 0; j < 4; ++j) acc[i][j] = (f32x4){0.f, 0.f, 0.f, 0.f};

  gemm256_core(A, Bm, DD, DD / 64, m0, n0, As, Bs, acc);

  const int tid = threadIdx.x, wave = tid >> 6, lane = tid & 63;
  const int l15 = lane & 15, quad = lane >> 4;
  const int wm = ((wave >> 2) & 1) << 4, wn = (wave & 3) << 4;
#pragma unroll
  for (int i = 0; i < 8; ++i)
#pragma unroll
    for (int j = 0; j < 4; ++j)
#pragma unroll
      for (int r = 0; r < 4; ++r) {
        const int row = ROW256(i, r);
        const int col = COL256(j);
        const float v = acc[i][j][r] + (bias_row ? bias[row] : bias[col]);
        C[(size_t)row * ldc + col] = (bf16_t)v;
      }
}

// ---------------- pass 1: S = exp(mask ? QK^T*scale : 0) + rowsum partials ----
// grid (4, 4, LB*NH).  rs layout: [z][ntile(4)][wn(4)][LQ] f32 (16 slots/z).
__global__ __launch_bounds__(512, 2) void gemm_qk(
    const bf16_t* __restrict__ Q, const bf16_t* __restrict__ K,
    const int* __restrict__ mask, bf16_t* __restrict__ S, float* __restrict__ rs)
{
  const int z = blockIdx.z, bb = z >> 3, by = blockIdx.y;
  const bf16_t* Az = Q + (size_t)z * LQ * DD;
  const bf16_t* Bz = K + (size_t)z * LK * DD;
  bf16_t* Sz = S + (size_t)z * LQ * LK;
  const int* mz = mask + (size_t)bb * LQ * LK;

  const int m0 = blockIdx.x * 256, n0 = by * 256;
  __shared__ __align__(16) bf16_t As[32768];
  __shared__ __align__(16) bf16_t Bs[32768];
  f32x4 acc[8][4];
#pragma unroll
  for (int i = 0; i < 8; ++i)
#pragma unroll
    for (int j = 0; j < 4; ++j) acc[i][j] = (f32x4){0.f, 0.f, 0.f, 0.f};

  gemm256_core(Az, Bz, DD, DD / 64, m0, n0, As, Bs, acc);

  const int tid = threadIdx.x, wave = tid >> 6, lane = tid & 63;
  const int l15 = lane & 15, quad = lane >> 4;
  const int wm = ((wave >> 2) & 1) << 4, wn = (wave & 3) << 4;
  float* rsz = rs + (((size_t)z * 4 + by) * 4 + (wave & 3)) * LQ;
  const float scale = 0.04419417382415922f;  // 1/sqrt(512)

#pragma unroll
  for (int i = 0; i < 8; ++i)
#pragma unroll
    for (int r = 0; r < 4; ++r) {
      const int row = ROW256(i, r);
      float rsum = 0.f;
#pragma unroll
      for (int j = 0; j < 4; ++j) {
        const int col = COL256(j);
        const int mv = mz[(size_t)row * LK + col];
        const float p = mv ? __expf(acc[i][j][r] * scale) : 0.f;
        rsum += p;
        Sz[(size_t)row * LK + col] = (bf16_t)p;
      }
      rsum += __shfl_xor(rsum, 1);
      rsum += __shfl_xor(rsum, 2);
      rsum += __shfl_xor(rsum, 4);
      rsum += __shfl_xor(rsum, 8);
      if (l15 == 0) rsz[row] = rsum;   // slot owned by (block, wave-col), no race
    }
}

// ---------------- pass 2: ctx = (S * inv_rowsum) . V  (old 128^2 core) ----
__global__ __launch_bounds__(256, 4) void gemm_pv(
    const bf16_t* __restrict__ S, const bf16_t* __restrict__ Vt,
    const float* __restrict__ rs, bf16_t* __restrict__ ctx)
{
  const int z = blockIdx.z, bb = z >> 3, hh = z & 7;
  const bf16_t* Az = S + (size_t)z * LQ * LK;
  const bf16_t* Bz = Vt + (size_t)z * DD * LK;
  bf16_t* Cz = ctx + (size_t)bb * LQ * (NH * DD) + (size_t)hh * DD;

  const int m0 = blockIdx.x * 128, n0 = blockIdx.y * 128;
  __shared__ __align__(16) bf16_t As[128 * 64];
  __shared__ __align__(16) bf16_t Bs[128 * 64];
  __shared__ float invs[128];

  const int tid = threadIdx.x;
  if (tid < 128) {   // rowsum reduce for this block's 128 rows
    const float* p = rs + (size_t)z * 16 * LQ + (m0 + tid);
    float tot = 0.f;
#pragma unroll
    for (int s = 0; s < 16; ++s) tot += p[s * LQ];
    invs[tid] = 1.f / tot;
  }
  // visibility guaranteed by gemm_core's internal barriers before epilogue

  f32x4 acc[4][4];
#pragma unroll
  for (int i = 0; i < 4; ++i)
#pragma unroll
    for (int j = 0; j < 4; ++j) acc[i][j] = (f32x4){0.f, 0.f, 0.f, 0.f};

  gemm_core(Az, Bz, LK, LK, m0, n0, As, Bs, acc);

  const int wave = tid >> 6, lane = tid & 63;
  const int l15 = lane & 15, quad = lane >> 4;
  const int wm = (wave & 1) * 64, wn = (wave >> 1) * 64;

#pragma unroll
  for (int i = 0; i < 4; ++i)
#pragma unroll
    for (int r = 0; r < 4; ++r) {
      const int lrow = wm + i * 16 + quad * 4 + r;
      const float iv = invs[lrow];
#pragma unroll
      for (int j = 0; j < 4; ++j) {
        const int col = n0 + wn + j * 16 + l15;
        Cz[(size_t)(m0 + lrow) * (NH * DD) + col] = (bf16_t)(acc[i][j][r] * iv);
      }
    }
}

// ---------------- out-projection, split-K=4, 256^2 8-phase ----------------
// grid (32, 2, 4).  partial[ks] : [8192,512] f32.
__global__ __launch_bounds__(512, 2) void gemm_outk(
    const bf16_t* __restrict__ ctx, const bf16_t* __restrict__ wp,
    float* __restrict__ partial)
{
  const int ks = blockIdx.z;
  const bf16_t* A = ctx + ks * 1024;
  const bf16_t* B = wp + ks * 1024;
  float* P = partial + (size_t)ks * B_DIM * LQ * DD;

  const int m0 = blockIdx.x * 256, n0 = blockIdx.y * 256;
  __shared__ __align__(16) bf16_t As[32768];
  __shared__ __align__(16) bf16_t Bs[32768];
  f32x4 acc[8][4];
#pragma unroll
  for (int i = 0; i < 8; ++i)
#pragma unroll
    for (int j = 0; j < 4; ++j) acc[i][j] = (f32x4){0.f, 0.f, 0.f, 0.f};

  gemm256_core(A, B, NH * DD, 1024 / 64, m0, n0, As, Bs, acc);

  const int tid = threadIdx.x, wave = tid >> 6, lane = tid & 63;
  const int l15 = lane & 15, quad = lane >> 4;
  const int wm = ((wave >> 2) & 1) << 4, wn = (wave & 3) << 4;
#pragma unroll
  for (int i = 0; i < 8; ++i)
#pragma unroll
    for (int j = 0; j < 4; ++j)
#pragma unroll
      for (int r = 0; r < 4; ++r) {
        const int row = ROW256(i, r);
        const int col = COL256(j);
        P[(size_t)row * DD + col] = acc[i][j][r];
      }
}

__global__ void reduce_out(const float* __restrict__ p, const float* __restrict__ bp,
                           float* __restrict__ out) {
  const int N = B_DIM * LQ * DD;
  int i = (blockIdx.x * 256 + threadIdx.x) * 4;
  float4 a = *(const float4*)(p + i);
  float4 b = *(const float4*)(p + N + i);
  float4 c = *(const float4*)(p + 2 * N + i);
  float4 d = *(const float4*)(p + 3 * N + i);
  const float4 bb4 = *(const float4*)(bp + (i & 511));
  float4 r;
  r.x = a.x + b.x + c.x + d.x + bb4.x;
  r.y = a.y + b.y + c.y + d.y + bb4.y;
  r.z = a.z + b.z + c.z + d.z + bb4.z;
  r.w = a.w + b.w + c.w + d.w + bb4.w;
  *(float4*)(out + i) = r;
}

// ---------------- host launcher ----------------
extern "C" void kernel_launch(void* const* d_in, const int* in_sizes, int n_in,
                              void* d_out, int out_size, void* d_ws, size_t ws_size,
                              hipStream_t stream) {
  const float* x      = (const float*)d_in[0];
  const float* states = (const float*)d_in[1];
  const int*   mask   = (const int*)d_in[2];
  const float* Wq     = (const float*)d_in[3];
  const float* bq     = (const float*)d_in[4];
  const float* Wk     = (const float*)d_in[5];
  const float* bk     = (const float*)d_in[6];
  const float* Wv     = (const float*)d_in[7];
  const float* bv     = (const float*)d_in[8];
  const float* Wp     = (const float*)d_in[9];
  const float* bp     = (const float*)d_in[10];
  float* out = (float*)d_out;

  // Workspace layout (ends at exactly 167,772,160 B = 160 MiB, proven safe):
  //   ctx 64MB @ 0 ; wqb/wkb/wvb 4MB each @ 64M..76M
  //   Qc 16MB @ 76M (wpb reuses) ; Kc 16MB @ 92M ; Vtc 16MB @ 108M
  //   S 32MB @ 124M ; xcb 2MB @ 156M ; scb 2MB @ 158M
  //   out-proj fp32 partials (64MB) reuse Kc/Vtc/S after chunks
  //   rowsum partials (1MB) live in d_out (16MB) until reduce_out
  char* ws = (char*)d_ws;
  bf16_t* ctxb = (bf16_t*)(ws + 0);
  bf16_t* wqb  = (bf16_t*)(ws + 67108864);
  bf16_t* wkb  = (bf16_t*)(ws + 71303168);
  bf16_t* wvb  = (bf16_t*)(ws + 75497472);
  bf16_t* Qc   = (bf16_t*)(ws + 79691776);
  bf16_t* Kc   = (bf16_t*)(ws + 96468992);
  bf16_t* Vtc  = (bf16_t*)(ws + 113246208);
  bf16_t* Sb   = (bf16_t*)(ws + 130023424);
  bf16_t* xcb  = (bf16_t*)(ws + 163577856);
  bf16_t* scb  = (bf16_t*)(ws + 165675008);
  bf16_t* wpb  = Qc;                         // dead Qc region after chunks
  float*  pbuf = (float*)(ws + 96468992);    // dead Kc/Vtc/S region after chunks
  float*  rsum = out;                        // [16][16][LQ] = 1MB in d_out

  const int n_w = NH * DD * DD;          // 2,097,152
  const int n_xc = LB * LQ * DD;         // 1,048,576 per chunk

  cvt_w3<<<dim3(n_w / 1024, 3), 256, 0, stream>>>(Wq, Wk, Wv, wqb, wkb, wvb, n_w);

  for (int c = 0; c < NCH; ++c) {
    const float* xc = x + (size_t)c * LB * LQ * DD;
    const float* sc = states + (size_t)c * LB * LK * DD;
    const int* mc = mask + (size_t)c * LB * LQ * LK;
    bf16_t* ctxc = ctxb + (size_t)c * LB * LQ * (NH * DD);

    cvt_pair<<<dim3(n_xc / 1024, 2), 256, 0, stream>>>(xc, xcb, sc, scb, n_xc);

    // fused Q/K/Vt projections: 384 blocks x 512 thr (256^2 tiles)
    gemm_qkv<<<dim3(8, 3 * LB * NH), 512, 0, stream>>>(
        xcb, scb, wqb, wkb, wvb, bq, bk, bv, Qc, Kc, Vtc);

    // attention as two GEMM passes
    gemm_qk<<<dim3(4, 4, LB * NH), 512, 0, stream>>>(Qc, Kc, mc, Sb, rsum);
    gemm_pv<<<dim3(8, 4, LB * NH), 256, 0, stream>>>(Sb, Vtc, rsum, ctxc);
  }

  // out = ctx @ Wp^T + bp : split-K=4 (256 blocks, 256^2 tiles) + reduce
  cvt_f32_bf16<<<n_w / 1024, 256, 0, stream>>>(Wp, wpb, n_w);
  gemm_outk<<<dim3(32, 2, 4), 512, 0, stream>>>(ctxb, wpb, pbuf);
  reduce_out<<<(B_DIM * LQ * DD) / 1024, 256, 0, stream>>>(pbuf, bp, out);
}

// Round 2
// 640.475 us; speedup vs baseline: 1.0293x; 1.0293x over previous
//
#include <hip/hip_runtime.h>
#include <hip/hip_bf16.h>

typedef __bf16 bf16_t;
typedef __bf16 bf16x8 __attribute__((ext_vector_type(8)));
typedef float f32x4 __attribute__((ext_vector_type(4)));

#define B_DIM 8
#define LQ 1024
#define LK 1024
#define DD 512
#define NH 8
#define LB 2          // batches per chunk
#define NCH 4         // chunks

static __device__ __forceinline__ f32x4 mfma_bf16(bf16x8 a, bf16x8 b, f32x4 c) {
  return __builtin_amdgcn_mfma_f32_16x16x32_bf16(a, b, c, 0, 0, 0);
}

// async global->LDS, 16B per lane (wave-uniform LDS base + lane*16)
static __device__ __forceinline__ void gld_lds16(const bf16_t* g, bf16_t* l) {
  __builtin_amdgcn_global_load_lds(
      (const __attribute__((address_space(1))) void*)g,
      (__attribute__((address_space(3))) void*)l, 16, 0, 0);
}

// ---------------- fp32 -> bf16 conversions ----------------
__global__ void cvt_pair(const float* __restrict__ s0, bf16_t* __restrict__ d0,
                         const float* __restrict__ s1, bf16_t* __restrict__ d1, int n) {
  const float* s = blockIdx.y ? s1 : s0;
  bf16_t* d = blockIdx.y ? d1 : d0;
  int i = (blockIdx.x * 256 + threadIdx.x) * 4;
  if (i < n) {
    const float4 f = *(const float4*)(s + i);
    bf16_t* p = d + i;
    p[0] = (bf16_t)f.x; p[1] = (bf16_t)f.y; p[2] = (bf16_t)f.z; p[3] = (bf16_t)f.w;
  }
}

__global__ void cvt_w3(const float* __restrict__ s0, const float* __restrict__ s1,
                       const float* __restrict__ s2, bf16_t* __restrict__ d0,
                       bf16_t* __restrict__ d1, bf16_t* __restrict__ d2, int n) {
  const float* s = (blockIdx.y == 0) ? s0 : (blockIdx.y == 1) ? s1 : s2;
  bf16_t* d = (blockIdx.y == 0) ? d0 : (blockIdx.y == 1) ? d1 : d2;
  int i = (blockIdx.x * 256 + threadIdx.x) * 4;
  if (i < n) {
    const float4 f = *(const float4*)(s + i);
    bf16_t* p = d + i;
    p[0] = (bf16_t)f.x; p[1] = (bf16_t)f.y; p[2] = (bf16_t)f.z; p[3] = (bf16_t)f.w;
  }
}

__global__ void cvt_f32_bf16(const float* __restrict__ s, bf16_t* __restrict__ d, int n) {
  int i = (blockIdx.x * 256 + threadIdx.x) * 4;
  if (i < n) {
    const float4 f = *(const float4*)(s + i);
    bf16_t* p = d + i;
    p[0] = (bf16_t)f.x; p[1] = (bf16_t)f.y; p[2] = (bf16_t)f.z; p[3] = (bf16_t)f.w;
  }
}

// mask int32 -> int8 (values 0/1): 4x less HBM traffic in gemm_qk, L2-resident
__global__ void cvt_mask(const int* __restrict__ m, unsigned char* __restrict__ d, int n) {
  int i = (blockIdx.x * 256 + threadIdx.x) * 4;
  if (i < n) {
    const int4 v = *(const int4*)(m + i);
    uchar4 o;
    o.x = (unsigned char)v.x; o.y = (unsigned char)v.y;
    o.z = (unsigned char)v.z; o.w = (unsigned char)v.w;
    *(uchar4*)(d + i) = o;
  }
}

// ======================================================================
// OLD 128x128 / BK=64 core (kept for gemm_pv: 256^2 grid would be only
// 128 blocks = half the CUs).
// ======================================================================
static __device__ __forceinline__ void gemm_core(
    const bf16_t* __restrict__ A, const bf16_t* __restrict__ B, int ld, int klen,
    int m0, int n0, bf16_t* As, bf16_t* Bs, f32x4 (&acc)[4][4])
{
  const int tid = threadIdx.x;
  const int wave = tid >> 6, lane = tid & 63;
  const int l15 = lane & 15, quad = lane >> 4;
  const int wm = (wave & 1) * 64, wn = (wave >> 1) * 64;

  const int r0 = tid >> 3;        // + p*32 per pass
  const int c8s = tid & 7;        // stored chunk index
  bf16_t* Asl = As + tid * 8;
  bf16_t* Bsl = Bs + tid * 8;

  for (int k0 = 0; k0 < klen; k0 += 64) {
    __syncthreads();
#pragma unroll
    for (int p = 0; p < 4; ++p) {
      const int r = r0 + p * 32;
      const int gc = ((c8s ^ (r & 7)) * 8) + k0;
      gld_lds16(A + (size_t)(m0 + r) * ld + gc, Asl + p * 2048);
      gld_lds16(B + (size_t)(n0 + r) * ld + gc, Bsl + p * 2048);
    }
    __syncthreads();  // drains vmcnt
#pragma unroll
    for (int ks = 0; ks < 2; ++ks) {
      bf16x8 af[4], bfr[4];
#pragma unroll
      for (int i = 0; i < 4; ++i) {
        const int r = wm + i * 16 + l15;
        af[i] = *(const bf16x8*)&As[(r * 8 + ((ks * 4 + quad) ^ (r & 7))) * 8];
      }
#pragma unroll
      for (int j = 0; j < 4; ++j) {
        const int r = wn + j * 16 + l15;
        bfr[j] = *(const bf16x8*)&Bs[(r * 8 + ((ks * 4 + quad) ^ (r & 7))) * 8];
      }
#pragma unroll
      for (int i = 0; i < 4; ++i)
#pragma unroll
        for (int j = 0; j < 4; ++j)
          acc[i][j] = mfma_bf16(af[i], bfr[j], acc[i][j]);
    }
  }
}

// ======================================================================
// 256x256 / BK=64 / 8-wave / 8-phase core — m201-FAITHFUL revision.
//
// R1 post-mortem: caching both A-halves across the K-tile (af[2][4][2],
// 64 VGPR) pushed the wave to the 256-reg launch_bounds wall -> spills ->
// MfmaUtil 12%.  m201's counts (12/4/12/4 ds_reads/phase) imply A-half
// reloaded at each m-half switch, B-half reloaded EVERY phase.  Registers:
// af[4][2]=32 + bfr[2][2]=16 VGPR + acc 128 AGPR ~ 200 total, comfortable.
//
// Phase order (m0n0)(m0n1)(m1n0)(m1n1); per-phase:
//   P0: RD_A(0) 8 + RD_B(0) 4; STG B1(j+1);  lgkm(8); bar; lgkm(0); 16 MFMA; bar
//   P1: RD_B(1) 4;             STG A0(j+2);           bar; lgkm(0); 16 MFMA; bar
//   P2: RD_A(1) 8 + RD_B(0) 4;               lgkm(8); bar; lgkm(0); 16 MFMA; bar
//   P3: RD_B(1) 4;             STG B0,A1(j+2);        bar; lgkm(0); 16 MFMA;
//       VMC(6); bar
// Race-safety: region R's kt-overwrite is issued only after the trailing
// barrier of R's last reading phase (A0 last read P0 -> staged P1; B0 last
// read P2 -> staged P3; A1 last read P2 -> staged P3; B1 last read P3 ->
// its j+1 copy staged at next tile's P0).  End-of-tile VMC(6) leaves
// exactly the 6 loads for j+2 {A0,B0,A1} in flight and proves everything
// needed for j+1 (incl. B1(j+1) staged this tile's P0) has landed.
// Never vmcnt(0) in steady state.
// ======================================================================
#define SBAR() __builtin_amdgcn_s_barrier()
#define SETPRIO(x) __builtin_amdgcn_s_setprio(x)
#define LGKM0() asm volatile("s_waitcnt lgkmcnt(0)" ::: "memory")
#define LGKM8() asm volatile("s_waitcnt lgkmcnt(8)" ::: "memory")
#define VMC(n) asm volatile("s_waitcnt vmcnt(" #n ")" ::: "memory")

static __device__ __forceinline__ void gemm256_core(
    const bf16_t* __restrict__ A, const bf16_t* __restrict__ Bm,
    const int ld, const int nkt, const int m0, const int n0,
    bf16_t* __restrict__ As, bf16_t* __restrict__ Bs, f32x4 (&acc)[8][4])
{
  const int tid = threadIdx.x;
  const int wave = tid >> 6, lane = tid & 63;
  const int l15 = lane & 15, quad = lane >> 4;
  const int wm = ((wave >> 2) & 1) << 4;   // 0 / 16
  const int wn = (wave & 3) << 4;          // 0 / 16 / 32 / 48

  // staging: 1024 slots per 128x64 half-tile, 512 threads x 2 passes
  const int s1 = tid + 512;
  const int r0 = tid >> 3, r1 = s1 >> 3;
  const int g0 = ((tid & 7) ^ (r0 & 7)) << 3;
  const int g1 = ((s1 & 7) ^ (r1 & 7)) << 3;
  const bf16_t* pa0 = A + (size_t)(m0 + r0) * ld + g0;
  const bf16_t* pa1 = A + (size_t)(m0 + r1) * ld + g1;
  const bf16_t* pb0 = Bm + (size_t)(n0 + r0) * ld + g0;
  const bf16_t* pb1 = Bm + (size_t)(n0 + r1) * ld + g1;
  const size_t hgl = (size_t)128 * ld;     // global step per 128-row half
  bf16_t* la = As + tid * 8;
  bf16_t* lb = Bs + tid * 8;

#define STG_A(kt, h) do { const int _o = (((kt) & 1) << 14) + ((h) << 13); \
    const size_t _g = (size_t)(h) * hgl + ((size_t)(kt) << 6); \
    gld_lds16(pa0 + _g, la + _o); gld_lds16(pa1 + _g, la + _o + 4096); } while (0)
#define STG_B(kt, h) do { const int _o = (((kt) & 1) << 14) + ((h) << 13); \
    const size_t _g = (size_t)(h) * hgl + ((size_t)(kt) << 6); \
    gld_lds16(pb0 + _g, lb + _o); gld_lds16(pb1 + _g, lb + _o + 4096); } while (0)

  bf16x8 af[4][2];    // current m-half A frags (32 VGPR)
  bf16x8 bfr[2][2];   // current n-half B frags (16 VGPR)

#define RD_A(mh) do { _Pragma("unroll") for (int a_ = 0; a_ < 4; ++a_) { \
    const int rl = wm + a_ * 32 + l15; \
    const int rb = sb + ((mh) << 13) + rl * 64; \
    _Pragma("unroll") for (int ks_ = 0; ks_ < 2; ++ks_) \
      af[a_][ks_] = *(const bf16x8*)&As[rb + (((ks_ * 4 + quad) ^ (rl & 7)) << 3)]; \
  } } while (0)
#define RD_B(nh) do { _Pragma("unroll") for (int b_ = 0; b_ < 2; ++b_) { \
    const int rl = wn + b_ * 64 + l15; \
    const int rb = sb + ((nh) << 13) + rl * 64; \
    _Pragma("unroll") for (int ks_ = 0; ks_ < 2; ++ks_) \
      bfr[b_][ks_] = *(const bf16x8*)&Bs[rb + (((ks_ * 4 + quad) ^ (rl & 7)) << 3)]; \
  } } while (0)
#define MMA(mh, nh) do { _Pragma("unroll") for (int ks_ = 0; ks_ < 2; ++ks_) \
    _Pragma("unroll") for (int a_ = 0; a_ < 4; ++a_) \
    _Pragma("unroll") for (int b_ = 0; b_ < 2; ++b_) \
      acc[(mh) * 4 + a_][(nh) * 2 + b_] = \
          mfma_bf16(af[a_][ks_], bfr[b_][ks_], acc[(mh) * 4 + a_][(nh) * 2 + b_]); \
  } while (0)

  // prologue: j0 fully (8 loads) + j1 partial {A0,B0,A1} (6 loads);
  // B1(1) is staged at j0's P0 per the steady-state schedule.
  STG_A(0, 0); STG_B(0, 0); STG_A(0, 1); STG_B(0, 1);
  if (nkt > 1) {
    STG_A(1, 0); STG_B(1, 0); STG_A(1, 1);
    VMC(6);            // j0's 8 landed, j1's 6 in flight
  } else {
    VMC(0);
  }
  SBAR();

#pragma unroll 2
  for (int j = 0; j < nkt; ++j) {
    const int sb = (j & 1) << 14;
    const bool s1ok = (j + 1) < nkt, s2ok = (j + 2) < nkt;
    // ---- P0: Q(m0,n0); stage B1(j+1) (region last read at (j-1) P3)
    RD_A(0); RD_B(0);
    if (s1ok) STG_B(j + 1, 1);
    LGKM8();
    SBAR(); LGKM0();
    SETPRIO(1); MMA(0, 0); SETPRIO(0);
    SBAR();
    // ---- P1: Q(m0,n1); stage A0(j+2) (region last read at P0)
    RD_B(1);
    if (s2ok) STG_A(j + 2, 0);
    SBAR(); LGKM0();
    SETPRIO(1); MMA(0, 1); SETPRIO(0);
    SBAR();
    // ---- P2: Q(m1,n0); no staging
    RD_A(1); RD_B(0);
    LGKM8();
    SBAR(); LGKM0();
    SETPRIO(1); MMA(1, 0); SETPRIO(0);
    SBAR();
    // ---- P3: Q(m1,n1); stage B0,A1(j+2) (regions last read at P2)
    RD_B(1);
    if (s2ok) { STG_B(j + 2, 0); STG_A(j + 2, 1); }
    SBAR(); LGKM0();
    SETPRIO(1); MMA(1, 1); SETPRIO(0);
    if (s1ok) {
      if (s2ok) { VMC(6); } else { VMC(0); }  // prove j+1 landed, keep j+2 in flight
      SBAR();
    }
  }
#undef STG_A
#undef STG_B
#undef RD_A
#undef RD_B
#undef MMA
}

// C row/col for acc[i][j] reg r (C/D map: col=lane&15, row=(lane>>4)*4+reg)
#define ROW256(i, r) (m0 + (((i) >> 2) << 7) + wm + ((i) & 3) * 32 + quad * 4 + (r))
#define COL256(j)    (n0 + (((j) >> 1) << 7) + wn + ((j) & 1) * 64 + l15)

// ---------------- fused Q/K/Vt projections (256^2 8-phase) ----------------
// grid (8, 3*LB*NH).  blockIdx.y = role*16 + z, z = bb*NH+hh.
__global__ __launch_bounds__(512, 2) void gemm_qkv(
    const bf16_t* __restrict__ xcb, const bf16_t* __restrict__ scb,
    const bf16_t* __restrict__ wq, const bf16_t* __restrict__ wk,
    const bf16_t* __restrict__ wv,
    const float* __restrict__ bq, const float* __restrict__ bk,
    const float* __restrict__ bv,
    bf16_t* __restrict__ Qc, bf16_t* __restrict__ Kc, bf16_t* __restrict__ Vtc)
{
  const int role = blockIdx.y >> 4, z = blockIdx.y & 15;
  const int bb = z >> 3, hh = z & 7;
  const int tx = blockIdx.x;

  const bf16_t* A; const bf16_t* Bm; const float* bias; bf16_t* C;
  int m0, n0, ldc, bias_row;
  if (role == 0) {
    A = xcb + (size_t)bb * LQ * DD; Bm = wq + (size_t)hh * DD * DD;
    bias = bq + hh * DD; C = Qc + (size_t)z * LQ * DD;
    m0 = (tx >> 1) * 256; n0 = (tx & 1) * 256; ldc = DD; bias_row = 0;
  } else if (role == 1) {
    A = scb + (size_t)bb * LK * DD; Bm = wk + (size_t)hh * DD * DD;
    bias = bk + hh * DD; C = Kc + (size_t)z * LK * DD;
    m0 = (tx >> 1) * 256; n0 = (tx & 1) * 256; ldc = DD; bias_row = 0;
  } else {
    A = wv + (size_t)hh * DD * DD; Bm = scb + (size_t)bb * LK * DD;
    bias = bv + hh * DD; C = Vtc + (size_t)z * DD * LK;
    m0 = (tx & 1) * 256; n0 = (tx >> 1) * 256; ldc = LK; bias_row = 1;
  }

  __shared__ __align__(16) bf16_t As[32768];   // 64 KiB
  __shared__ __align__(16) bf16_t Bs[32768];   // 64 KiB
  f32x4 acc[8][4];
#pragma unroll
  for (int i = 0; i < 8; ++i)
#pragma unroll
    for (int j = 0; j < 4; ++j) acc[i][j] = (f32x4){0.f, 0.f, 0.f, 0.f};

  gemm256_core(A, Bm, DD, DD / 64, m0, n0, As, Bs, acc);

  const int tid = threadIdx.x, wave = tid >> 6, lane = tid & 63;
  const int l15 = lane & 15, quad = lane >> 4;
  const int wm = ((wave >> 2) & 1) << 4, wn = (wave & 3) << 4;
#pragma unroll
  for (int i = 0; i < 8; ++i)
#pragma unroll
    for (int j = 0; j < 4; ++j)
#pragma unroll
      for (int r = 0; r < 4; ++r) {
        const int row = ROW256(i, r);
        const int col = COL256(j);
        const float v = acc[i][j][r] + (bias_row ? bias[row] : bias[col]);
        C[(size_t)row * ldc + col] = (bf16_t)v;
      }
}

// ---------------- pass 1: S = exp(mask ? QK^T*scale : 0) + rowsum partials ----
// grid (4, 4, LB*NH).  rs layout: [z][ntile(4)][wn(4)][LQ] f32 (16 slots/z).
__global__ __launch_bounds__(512, 2) void gemm_qk(
    const bf16_t* __restrict__ Q, const bf16_t* __restrict__ K,
    const unsigned char* __restrict__ maskb, bf16_t* __restrict__ S,
    float* __restrict__ rs)
{
  const int z = blockIdx.z, bb = z >> 3, by = blockIdx.y;
  const bf16_t* Az = Q + (size_t)z * LQ * DD;
  const bf16_t* Bz = K + (size_t)z * LK * DD;
  bf16_t* Sz = S + (size_t)z * LQ * LK;
  const unsigned char* mz = maskb + (size_t)bb * LQ * LK;

  const int m0 = blockIdx.x * 256, n0 = by * 256;
  __shared__ __align__(16) bf16_t As[32768];
  __shared__ __align__(16) bf16_t Bs[32768];
  f32x4 acc[8][4];
#pragma unroll
  for (int i = 0; i < 8; ++i)
#pragma unroll
    for (int j = 0; j < 4; ++j) acc[i][j] = (f32x4){0.f, 0.f, 0.f, 0.f};

  gemm256_core(Az, Bz, DD, DD / 64, m0, n0, As, Bs, acc);

  const int tid = threadIdx.x, wave = tid >> 6, lane = tid & 63;
  const int l15 = lane & 15, quad = lane >> 4;
  const int wm = ((wave >> 2) & 1) << 4, wn = (wave & 3) << 4;
  float* rsz = rs + (((size_t)z * 4 + by) * 4 + (wave & 3)) * LQ;
  const float scale = 0.04419417382415922f;  // 1/sqrt(512)

#pragma unroll
  for (int i = 0; i < 8; ++i)
#pragma unroll
    for (int r = 0; r < 4; ++r) {
      const int row = ROW256(i, r);
      float rsum = 0.f;
#pragma unroll
      for (int j = 0; j < 4; ++j) {
        const int col = COL256(j);
        const int mv = mz[(size_t)row * LK + col];
        const float p = mv ? __expf(acc[i][j][r] * scale) : 0.f;
        rsum += p;
        Sz[(size_t)row * LK + col] = (bf16_t)p;
      }
      rsum += __shfl_xor(rsum, 1);
      rsum += __shfl_xor(rsum, 2);
      rsum += __shfl_xor(rsum, 4);
      rsum += __shfl_xor(rsum, 8);
      if (l15 == 0) rsz[row] = rsum;   // slot owned by (block, wave-col), no race
    }
}

// ---------------- pass 2: ctx = (S * inv_rowsum) . V  (old 128^2 core) ----
__global__ __launch_bounds__(256, 4) void gemm_pv(
    const bf16_t* __restrict__ S, const bf16_t* __restrict__ Vt,
    const float* __restrict__ rs, bf16_t* __restrict__ ctx)
{
  const int z = blockIdx.z, bb = z >> 3, hh = z & 7;
  const bf16_t* Az = S + (size_t)z * LQ * LK;
  const bf16_t* Bz = Vt + (size_t)z * DD * LK;
  bf16_t* Cz = ctx + (size_t)bb * LQ * (NH * DD) + (size_t)hh * DD;

  const int m0 = blockIdx.x * 128, n0 = blockIdx.y * 128;
  __shared__ __align__(16) bf16_t As[128 * 64];
  __shared__ __align__(16) bf16_t Bs[128 * 64];
  __shared__ float invs[128];

  const int tid = threadIdx.x;
  if (tid < 128) {   // rowsum reduce for this block's 128 rows
    const float* p = rs + (size_t)z * 16 * LQ + (m0 + tid);
    float tot = 0.f;
#pragma unroll
    for (int s = 0; s < 16; ++s) tot += p[s * LQ];
    invs[tid] = 1.f / tot;
  }
  // visibility guaranteed by gemm_core's internal barriers before epilogue

  f32x4 acc[4][4];
#pragma unroll
  for (int i = 0; i < 4; ++i)
#pragma unroll
    for (int j = 0; j < 4; ++j) acc[i][j] = (f32x4){0.f, 0.f, 0.f, 0.f};

  gemm_core(Az, Bz, LK, LK, m0, n0, As, Bs, acc);

  const int wave = tid >> 6, lane = tid & 63;
  const int l15 = lane & 15, quad = lane >> 4;
  const int wm = (wave & 1) * 64, wn = (wave >> 1) * 64;

#pragma unroll
  for (int i = 0; i < 4; ++i)
#pragma unroll
    for (int r = 0; r < 4; ++r) {
      const int lrow = wm + i * 16 + quad * 4 + r;
      const float iv = invs[lrow];
#pragma unroll
      for (int j = 0; j < 4; ++j) {
        const int col = n0 + wn + j * 16 + l15;
        Cz[(size_t)(m0 + lrow) * (NH * DD) + col] = (bf16_t)(acc[i][j][r] * iv);
      }
    }
}

// ---------------- out-projection, split-K=4, 256^2 8-phase ----------------
// grid (32, 2, 4).  partial[ks] : [8192,512] f32.
__global__ __launch_bounds__(512, 2) void gemm_outk(
    const bf16_t* __restrict__ ctx, const bf16_t* __restrict__ wp,
    float* __restrict__ partial)
{
  const int ks = blockIdx.z;
  const bf16_t* A = ctx + ks * 1024;
  const bf16_t* B = wp + ks * 1024;
  float* P = partial + (size_t)ks * B_DIM * LQ * DD;

  const int m0 = blockIdx.x * 256, n0 = blockIdx.y * 256;
  __shared__ __align__(16) bf16_t As[32768];
  __shared__ __align__(16) bf16_t Bs[32768];
  f32x4 acc[8][4];
#pragma unroll
  for (int i = 0; i < 8; ++i)
#pragma unroll
    for (int j = 0; j < 4; ++j) acc[i][j] = (f32x4){0.f, 0.f, 0.f, 0.f};

  gemm256_core(A, B, NH * DD, 1024 / 64, m0, n0, As, Bs, acc);

  const int tid = threadIdx.x, wave = tid >> 6, lane = tid & 63;
  const int l15 = lane & 15, quad = lane >> 4;
  const int wm = ((wave >> 2) & 1) << 4, wn = (wave & 3) << 4;
#pragma unroll
  for (int i = 0; i < 8; ++i)
#pragma unroll
    for (int j = 0; j < 4; ++j)
#pragma unroll
      for (int r = 0; r < 4; ++r) {
        const int row = ROW256(i, r);
        const int col = COL256(j);
        P[(size_t)row * DD + col] = acc[i][j][r];
      }
}

__global__ void reduce_out(const float* __restrict__ p, const float* __restrict__ bp,
                           float* __restrict__ out) {
  const int N = B_DIM * LQ * DD;
  int i = (blockIdx.x * 256 + threadIdx.x) * 4;
  float4 a = *(const float4*)(p + i);
  float4 b = *(const float4*)(p + N + i);
  float4 c = *(const float4*)(p + 2 * N + i);
  float4 d = *(const float4*)(p + 3 * N + i);
  const float4 bb4 = *(const float4*)(bp + (i & 511));
  float4 r;
  r.x = a.x + b.x + c.x + d.x + bb4.x;
  r.y = a.y + b.y + c.y + d.y + bb4.y;
  r.z = a.z + b.z + c.z + d.z + bb4.z;
  r.w = a.w + b.w + c.w + d.w + bb4.w;
  *(float4*)(out + i) = r;
}

// ---------------- host launcher ----------------
extern "C" void kernel_launch(void* const* d_in, const int* in_sizes, int n_in,
                              void* d_out, int out_size, void* d_ws, size_t ws_size,
                              hipStream_t stream) {
  const float* x      = (const float*)d_in[0];
  const float* states = (const float*)d_in[1];
  const int*   mask   = (const int*)d_in[2];
  const float* Wq     = (const float*)d_in[3];
  const float* bq     = (const float*)d_in[4];
  const float* Wk     = (const float*)d_in[5];
  const float* bk     = (const float*)d_in[6];
  const float* Wv     = (const float*)d_in[7];
  const float* bv     = (const float*)d_in[8];
  const float* Wp     = (const float*)d_in[9];
  const float* bp     = (const float*)d_in[10];
  float* out = (float*)d_out;

  // Workspace layout (ends at exactly 167,772,160 B = 160 MiB, proven safe):
  //   ctx 64MB @ 0 ; wqb/wkb/wvb 4MB each @ 64M..76M
  //   Qc 16MB @ 76M (wpb reuses) ; Kc 16MB @ 92M ; Vtc 16MB @ 108M
  //   S 32MB @ 124M ; xcb 2MB @ 156M ; scb 2MB @ 158M
  //   out-proj fp32 partials (64MB) reuse Kc/Vtc/S after chunks
  //   d_out (16MB) scratch: rowsum partials 1MB @ 0 ; mask-int8 2MB @ 1M
  char* ws = (char*)d_ws;
  bf16_t* ctxb = (bf16_t*)(ws + 0);
  bf16_t* wqb  = (bf16_t*)(ws + 67108864);
  bf16_t* wkb  = (bf16_t*)(ws + 71303168);
  bf16_t* wvb  = (bf16_t*)(ws + 75497472);
  bf16_t* Qc   = (bf16_t*)(ws + 79691776);
  bf16_t* Kc   = (bf16_t*)(ws + 96468992);
  bf16_t* Vtc  = (bf16_t*)(ws + 113246208);
  bf16_t* Sb   = (bf16_t*)(ws + 130023424);
  bf16_t* xcb  = (bf16_t*)(ws + 163577856);
  bf16_t* scb  = (bf16_t*)(ws + 165675008);
  bf16_t* wpb  = Qc;                         // dead Qc region after chunks
  float*  pbuf = (float*)(ws + 96468992);    // dead Kc/Vtc/S region after chunks
  float*  rsum = out;                        // [16][16][LQ] = 1MB in d_out
  unsigned char* mkb = (unsigned char*)out + (1 << 20);  // 2MB in d_out

  const int n_w = NH * DD * DD;          // 2,097,152
  const int n_xc = LB * LQ * DD;         // 1,048,576 per chunk
  const int n_mk = LB * LQ * LK;         // 2,097,152 per chunk

  cvt_w3<<<dim3(n_w / 1024, 3), 256, 0, stream>>>(Wq, Wk, Wv, wqb, wkb, wvb, n_w);

  for (int c = 0; c < NCH; ++c) {
    const float* xc = x + (size_t)c * LB * LQ * DD;
    const float* sc = states + (size_t)c * LB * LK * DD;
    const int* mc = mask + (size_t)c * LB * LQ * LK;
    bf16_t* ctxc = ctxb + (size_t)c * LB * LQ * (NH * DD);

    cvt_pair<<<dim3(n_xc / 1024, 2), 256, 0, stream>>>(xc, xcb, sc, scb, n_xc);
    cvt_mask<<<n_mk / 1024, 256, 0, stream>>>(mc, mkb, n_mk);

    // fused Q/K/Vt projections: 384 blocks x 512 thr (256^2 tiles)
    gemm_qkv<<<dim3(8, 3 * LB * NH), 512, 0, stream>>>(
        xcb, scb, wqb, wkb, wvb, bq, bk, bv, Qc, Kc, Vtc);

    // attention as two GEMM passes
    gemm_qk<<<dim3(4, 4, LB * NH), 512, 0, stream>>>(Qc, Kc, mkb, Sb, rsum);
    gemm_pv<<<dim3(8, 4, LB * NH), 256, 0, stream>>>(Sb, Vtc, rsum, ctxc);
  }

  // out = ctx @ Wp^T + bp : split-K=4 (256 blocks, 256^2 tiles) + reduce
  cvt_f32_bf16<<<n_w / 1024, 256, 0, stream>>>(Wp, wpb, n_w);
  gemm_outk<<<dim3(32, 2, 4), 512, 0, stream>>>(ctxb, wpb, pbuf);
  reduce_out<<<(B_DIM * LQ * DD) / 1024, 256, 0, stream>>>(pbuf, bp, out);
}

// Round 3
// 594.552 us; speedup vs baseline: 1.1088x; 1.0772x over previous
//
#include <hip/hip_runtime.h>
#include <hip/hip_bf16.h>

typedef __bf16 bf16_t;
typedef __bf16 bf16x8 __attribute__((ext_vector_type(8)));
typedef float f32x4 __attribute__((ext_vector_type(4)));

#define B_DIM 8
#define LQ 1024
#define LK 1024
#define DD 512
#define NH 8
#define LB 2          // batches per chunk
#define NCH 4         // chunks

static __device__ __forceinline__ f32x4 mfma_bf16(bf16x8 a, bf16x8 b, f32x4 c) {
  return __builtin_amdgcn_mfma_f32_16x16x32_bf16(a, b, c, 0, 0, 0);
}

// async global->LDS, 16B per lane (wave-uniform LDS base + lane*16)
static __device__ __forceinline__ void gld_lds16(const bf16_t* g, bf16_t* l) {
  __builtin_amdgcn_global_load_lds(
      (const __attribute__((address_space(1))) void*)g,
      (__attribute__((address_space(3))) void*)l, 16, 0, 0);
}

// ---------------- fp32 -> bf16 conversions ----------------
__global__ void cvt_pair(const float* __restrict__ s0, bf16_t* __restrict__ d0,
                         const float* __restrict__ s1, bf16_t* __restrict__ d1, int n) {
  const float* s = blockIdx.y ? s1 : s0;
  bf16_t* d = blockIdx.y ? d1 : d0;
  int i = (blockIdx.x * 256 + threadIdx.x) * 4;
  if (i < n) {
    const float4 f = *(const float4*)(s + i);
    bf16_t* p = d + i;
    p[0] = (bf16_t)f.x; p[1] = (bf16_t)f.y; p[2] = (bf16_t)f.z; p[3] = (bf16_t)f.w;
  }
}

__global__ void cvt_w3(const float* __restrict__ s0, const float* __restrict__ s1,
                       const float* __restrict__ s2, bf16_t* __restrict__ d0,
                       bf16_t* __restrict__ d1, bf16_t* __restrict__ d2, int n) {
  const float* s = (blockIdx.y == 0) ? s0 : (blockIdx.y == 1) ? s1 : s2;
  bf16_t* d = (blockIdx.y == 0) ? d0 : (blockIdx.y == 1) ? d1 : d2;
  int i = (blockIdx.x * 256 + threadIdx.x) * 4;
  if (i < n) {
    const float4 f = *(const float4*)(s + i);
    bf16_t* p = d + i;
    p[0] = (bf16_t)f.x; p[1] = (bf16_t)f.y; p[2] = (bf16_t)f.z; p[3] = (bf16_t)f.w;
  }
}

__global__ void cvt_f32_bf16(const float* __restrict__ s, bf16_t* __restrict__ d, int n) {
  int i = (blockIdx.x * 256 + threadIdx.x) * 4;
  if (i < n) {
    const float4 f = *(const float4*)(s + i);
    bf16_t* p = d + i;
    p[0] = (bf16_t)f.x; p[1] = (bf16_t)f.y; p[2] = (bf16_t)f.z; p[3] = (bf16_t)f.w;
  }
}

// mask int32 -> int8 (values 0/1): 4x less mask traffic in gemm_qk, L2-resident
__global__ void cvt_mask(const int* __restrict__ m, unsigned char* __restrict__ d, int n) {
  int i = (blockIdx.x * 256 + threadIdx.x) * 4;
  if (i < n) {
    const int4 v = *(const int4*)(m + i);
    uchar4 o;
    o.x = (unsigned char)v.x; o.y = (unsigned char)v.y;
    o.z = (unsigned char)v.z; o.w = (unsigned char)v.w;
    *(uchar4*)(d + i) = o;
  }
}

// ---------------- GEMM mainloop: BK=64, XOR-swizzled LDS ----------------
// C-tile 128x128, BK=64 (32 MFMA per barrier-pair), global_load_lds width-16.
// LDS layout: slot s in [0,1024) holds row r=s>>3, global col-chunk (s&7)^(r&7)
// (8 bf16 per chunk). global_load_lds forces dst=base+lane*16, so the swizzle
// permutes WHICH global chunk each lane fetches. Frag reads then spread the 16
// l15-lanes across all 8 bank groups -> conflict-free ds_read_b128.
static __device__ __forceinline__ void gemm_core(
    const bf16_t* __restrict__ A, const bf16_t* __restrict__ B, int ld, int klen,
    int m0, int n0, bf16_t* As, bf16_t* Bs, f32x4 (&acc)[4][4])
{
  const int tid = threadIdx.x;
  const int wave = tid >> 6, lane = tid & 63;
  const int l15 = lane & 15, quad = lane >> 4;
  const int wm = (wave & 1) * 64, wn = (wave >> 1) * 64;

  const int r0 = tid >> 3;        // + p*32 per pass
  const int c8s = tid & 7;        // stored chunk index
  bf16_t* Asl = As + tid * 8;
  bf16_t* Bsl = Bs + tid * 8;

  for (int k0 = 0; k0 < klen; k0 += 64) {
    __syncthreads();
#pragma unroll
    for (int p = 0; p < 4; ++p) {
      const int r = r0 + p * 32;
      const int gc = ((c8s ^ (r & 7)) * 8) + k0;
      gld_lds16(A + (size_t)(m0 + r) * ld + gc, Asl + p * 2048);
      gld_lds16(B + (size_t)(n0 + r) * ld + gc, Bsl + p * 2048);
    }
    __syncthreads();  // drains vmcnt
#pragma unroll
    for (int ks = 0; ks < 2; ++ks) {
      bf16x8 af[4], bfr[4];
#pragma unroll
      for (int i = 0; i < 4; ++i) {
        const int r = wm + i * 16 + l15;
        af[i] = *(const bf16x8*)&As[(r * 8 + ((ks * 4 + quad) ^ (r & 7))) * 8];
      }
#pragma unroll
      for (int j = 0; j < 4; ++j) {
        const int r = wn + j * 16 + l15;
        bfr[j] = *(const bf16x8*)&Bs[(r * 8 + ((ks * 4 + quad) ^ (r & 7))) * 8];
      }
#pragma unroll
      for (int i = 0; i < 4; ++i)
#pragma unroll
        for (int j = 0; j < 4; ++j)
          acc[i][j] = mfma_bf16(af[i], bfr[j], acc[i][j]);
    }
  }
}

// ---------------- fused Q/K/Vt projections ----------------
// grid (32, 3*LB*NH). blockIdx.y = role*16 + z, z = bb*NH+hh.
__global__ __launch_bounds__(256, 4) void gemm_qkv(
    const bf16_t* __restrict__ xcb, const bf16_t* __restrict__ scb,
    const bf16_t* __restrict__ wq, const bf16_t* __restrict__ wk,
    const bf16_t* __restrict__ wv,
    const float* __restrict__ bq, const float* __restrict__ bk,
    const float* __restrict__ bv,
    bf16_t* __restrict__ Qc, bf16_t* __restrict__ Kc, bf16_t* __restrict__ Vtc)
{
  const int role = blockIdx.y >> 4, z = blockIdx.y & 15;
  const int bb = z >> 3, hh = z & 7;
  const int tx = blockIdx.x;

  const bf16_t* A; const bf16_t* Bm; const float* bias; bf16_t* C;
  int m0, n0, ldc, bias_row;
  if (role == 0) {
    A = xcb + (size_t)bb * LQ * DD; Bm = wq + (size_t)hh * DD * DD;
    bias = bq + hh * DD; C = Qc + (size_t)z * LQ * DD;
    m0 = (tx >> 2) * 128; n0 = (tx & 3) * 128; ldc = DD; bias_row = 0;
  } else if (role == 1) {
    A = scb + (size_t)bb * LK * DD; Bm = wk + (size_t)hh * DD * DD;
    bias = bk + hh * DD; C = Kc + (size_t)z * LK * DD;
    m0 = (tx >> 2) * 128; n0 = (tx & 3) * 128; ldc = DD; bias_row = 0;
  } else {
    A = wv + (size_t)hh * DD * DD; Bm = scb + (size_t)bb * LK * DD;
    bias = bv + hh * DD; C = Vtc + (size_t)z * DD * LK;
    m0 = (tx & 3) * 128; n0 = (tx >> 2) * 128; ldc = LK; bias_row = 1;
  }

  __shared__ __align__(16) bf16_t As[128 * 64];
  __shared__ __align__(16) bf16_t Bs[128 * 64];
  f32x4 acc[4][4];
#pragma unroll
  for (int i = 0; i < 4; ++i)
#pragma unroll
    for (int j = 0; j < 4; ++j) acc[i][j] = (f32x4){0.f, 0.f, 0.f, 0.f};

  gemm_core(A, Bm, DD, DD, m0, n0, As, Bs, acc);

  const int tid = threadIdx.x, wave = tid >> 6, lane = tid & 63;
  const int l15 = lane & 15, quad = lane >> 4;
  const int wm = (wave & 1) * 64, wn = (wave >> 1) * 64;
#pragma unroll
  for (int i = 0; i < 4; ++i)
#pragma unroll
    for (int j = 0; j < 4; ++j)
#pragma unroll
      for (int r = 0; r < 4; ++r) {
        const int row = m0 + wm + i * 16 + quad * 4 + r;
        const int col = n0 + wn + j * 16 + l15;
        const float v = acc[i][j][r] + (bias_row ? bias[row] : bias[col]);
        C[(size_t)row * ldc + col] = (bf16_t)v;
      }
}

// ---------------- pass 1: S = exp(mask ? QK^T*scale : 0), rowsum partials ----
// grid (8, 8, LB*NH). rs layout: [z][ntile(8)][half(2)][LQ] f32; half = wave>>1
// (waves 0/2 and 1/3 cover same rows, different column halves -> separate slots).
__global__ __launch_bounds__(256, 4) void gemm_qk(
    const bf16_t* __restrict__ Q, const bf16_t* __restrict__ K,
    const unsigned char* __restrict__ maskb, bf16_t* __restrict__ S,
    float* __restrict__ rs)
{
  const int z = blockIdx.z, bb = z >> 3, nt = blockIdx.y;
  const bf16_t* Az = Q + (size_t)z * LQ * DD;
  const bf16_t* Bz = K + (size_t)z * LK * DD;
  bf16_t* Sz = S + (size_t)z * LQ * LK;
  const unsigned char* mz = maskb + (size_t)bb * LQ * LK;

  const int m0 = blockIdx.x * 128, n0 = nt * 128;
  __shared__ __align__(16) bf16_t As[128 * 64];
  __shared__ __align__(16) bf16_t Bs[128 * 64];
  f32x4 acc[4][4];
#pragma unroll
  for (int i = 0; i < 4; ++i)
#pragma unroll
    for (int j = 0; j < 4; ++j) acc[i][j] = (f32x4){0.f, 0.f, 0.f, 0.f};

  gemm_core(Az, Bz, DD, DD, m0, n0, As, Bs, acc);

  const int tid = threadIdx.x, wave = tid >> 6, lane = tid & 63;
  const int l15 = lane & 15, quad = lane >> 4;
  const int wm = (wave & 1) * 64, wn = (wave >> 1) * 64;
  float* rsz = rs + (((size_t)z * 8 + nt) * 2 + (wave >> 1)) * LQ;
  const float scale = 0.04419417382415922f;  // 1/sqrt(512)

#pragma unroll
  for (int i = 0; i < 4; ++i)
#pragma unroll
    for (int r = 0; r < 4; ++r) {
      const int row = m0 + wm + i * 16 + quad * 4 + r;
      float rsum = 0.f;
#pragma unroll
      for (int j = 0; j < 4; ++j) {
        const int col = n0 + wn + j * 16 + l15;
        const int mv = mz[(size_t)row * LK + col];
        const float p = mv ? __expf(acc[i][j][r] * scale) : 0.f;
        rsum += p;
        Sz[(size_t)row * LK + col] = (bf16_t)p;
      }
      rsum += __shfl_xor(rsum, 1);
      rsum += __shfl_xor(rsum, 2);
      rsum += __shfl_xor(rsum, 4);
      rsum += __shfl_xor(rsum, 8);
      if (l15 == 0) rsz[row] = rsum;   // block+half-owned slot, no race
    }
}

// ---------------- pass 2: ctx = (S * inv_rowsum) . V ----------------
// inv computed in-prologue from the 16 rs partials per row (no extra dispatch).
__global__ __launch_bounds__(256, 4) void gemm_pv(
    const bf16_t* __restrict__ S, const bf16_t* __restrict__ Vt,
    const float* __restrict__ rs, bf16_t* __restrict__ ctx)
{
  const int z = blockIdx.z, bb = z >> 3, hh = z & 7;
  const bf16_t* Az = S + (size_t)z * LQ * LK;
  const bf16_t* Bz = Vt + (size_t)z * DD * LK;
  bf16_t* Cz = ctx + (size_t)bb * LQ * (NH * DD) + (size_t)hh * DD;

  const int m0 = blockIdx.x * 128, n0 = blockIdx.y * 128;
  __shared__ __align__(16) bf16_t As[128 * 64];
  __shared__ __align__(16) bf16_t Bs[128 * 64];
  __shared__ float invs[128];

  const int tid = threadIdx.x;
  if (tid < 128) {   // rowsum reduce for this block's 128 rows
    const float* p = rs + (size_t)z * 16 * LQ + (m0 + tid);
    float tot = 0.f;
#pragma unroll
    for (int s = 0; s < 16; ++s) tot += p[s * LQ];
    invs[tid] = 1.f / tot;
  }
  // visibility guaranteed by gemm_core's internal barriers before epilogue

  f32x4 acc[4][4];
#pragma unroll
  for (int i = 0; i < 4; ++i)
#pragma unroll
    for (int j = 0; j < 4; ++j) acc[i][j] = (f32x4){0.f, 0.f, 0.f, 0.f};

  gemm_core(Az, Bz, LK, LK, m0, n0, As, Bs, acc);

  const int wave = tid >> 6, lane = tid & 63;
  const int l15 = lane & 15, quad = lane >> 4;
  const int wm = (wave & 1) * 64, wn = (wave >> 1) * 64;

#pragma unroll
  for (int i = 0; i < 4; ++i)
#pragma unroll
    for (int r = 0; r < 4; ++r) {
      const int lrow = wm + i * 16 + quad * 4 + r;
      const float iv = invs[lrow];
#pragma unroll
      for (int j = 0; j < 4; ++j) {
        const int col = n0 + wn + j * 16 + l15;
        Cz[(size_t)(m0 + lrow) * (NH * DD) + col] = (bf16_t)(acc[i][j][r] * iv);
      }
    }
}

// ---------------- out-projection, split-K=4 ----------------
// grid (64, 4, 4). partial[ks] : [8192,512] f32.
__global__ __launch_bounds__(256, 4) void gemm_outk(
    const bf16_t* __restrict__ ctx, const bf16_t* __restrict__ wp,
    float* __restrict__ partial)
{
  const int ks = blockIdx.z;
  const bf16_t* A = ctx + ks * 1024;
  const bf16_t* B = wp + ks * 1024;
  float* P = partial + (size_t)ks * B_DIM * LQ * DD;

  const int m0 = blockIdx.x * 128, n0 = blockIdx.y * 128;
  __shared__ __align__(16) bf16_t As[128 * 64];
  __shared__ __align__(16) bf16_t Bs[128 * 64];
  f32x4 acc[4][4];
#pragma unroll
  for (int i = 0; i < 4; ++i)
#pragma unroll
    for (int j = 0; j < 4; ++j) acc[i][j] = (f32x4){0.f, 0.f, 0.f, 0.f};

  gemm_core(A, B, NH * DD, 1024, m0, n0, As, Bs, acc);

  const int tid = threadIdx.x, wave = tid >> 6, lane = tid & 63;
  const int l15 = lane & 15, quad = lane >> 4;
  const int wm = (wave & 1) * 64, wn = (wave >> 1) * 64;
#pragma unroll
  for (int i = 0; i < 4; ++i)
#pragma unroll
    for (int j = 0; j < 4; ++j)
#pragma unroll
      for (int r = 0; r < 4; ++r) {
        const int row = m0 + wm + i * 16 + quad * 4 + r;
        const int col = n0 + wn + j * 16 + l15;
        P[(size_t)row * DD + col] = acc[i][j][r];
      }
}

__global__ void reduce_out(const float* __restrict__ p, const float* __restrict__ bp,
                           float* __restrict__ out) {
  const int N = B_DIM * LQ * DD;
  int i = (blockIdx.x * 256 + threadIdx.x) * 4;
  float4 a = *(const float4*)(p + i);
  float4 b = *(const float4*)(p + N + i);
  float4 c = *(const float4*)(p + 2 * N + i);
  float4 d = *(const float4*)(p + 3 * N + i);
  const float4 bb4 = *(const float4*)(bp + (i & 511));
  float4 r;
  r.x = a.x + b.x + c.x + d.x + bb4.x;
  r.y = a.y + b.y + c.y + d.y + bb4.y;
  r.z = a.z + b.z + c.z + d.z + bb4.z;
  r.w = a.w + b.w + c.w + d.w + bb4.w;
  *(float4*)(out + i) = r;
}

// ---------------- host launcher ----------------
extern "C" void kernel_launch(void* const* d_in, const int* in_sizes, int n_in,
                              void* d_out, int out_size, void* d_ws, size_t ws_size,
                              hipStream_t stream) {
  const float* x      = (const float*)d_in[0];
  const float* states = (const float*)d_in[1];
  const int*   mask   = (const int*)d_in[2];
  const float* Wq     = (const float*)d_in[3];
  const float* bq     = (const float*)d_in[4];
  const float* Wk     = (const float*)d_in[5];
  const float* bk     = (const float*)d_in[6];
  const float* Wv     = (const float*)d_in[7];
  const float* bv     = (const float*)d_in[8];
  const float* Wp     = (const float*)d_in[9];
  const float* bp     = (const float*)d_in[10];
  float* out = (float*)d_out;

  // Workspace layout (ends at exactly 167,772,160 B = 160 MiB, proven safe):
  //   ctx 64MB @ 0 ; wqb/wkb/wvb 4MB each @ 64M..76M
  //   Qc 16MB @ 76M (wpb reuses) ; Kc 16MB @ 92M ; Vtc 16MB @ 108M
  //   S 32MB @ 124M ; xcb 2MB @ 156M ; scb 2MB @ 158M
  //   out-proj fp32 partials (64MB) reuse Kc/Vtc/S after chunks
  //   d_out (16MB) scratch: rowsum partials 1MB @ 0 ; mask-int8 2MB @ 1M
  char* ws = (char*)d_ws;
  bf16_t* ctxb = (bf16_t*)(ws + 0);
  bf16_t* wqb  = (bf16_t*)(ws + 67108864);
  bf16_t* wkb  = (bf16_t*)(ws + 71303168);
  bf16_t* wvb  = (bf16_t*)(ws + 75497472);
  bf16_t* Qc   = (bf16_t*)(ws + 79691776);
  bf16_t* Kc   = (bf16_t*)(ws + 96468992);
  bf16_t* Vtc  = (bf16_t*)(ws + 113246208);
  bf16_t* Sb   = (bf16_t*)(ws + 130023424);
  bf16_t* xcb  = (bf16_t*)(ws + 163577856);
  bf16_t* scb  = (bf16_t*)(ws + 165675008);
  bf16_t* wpb  = Qc;                         // dead Qc region after chunks
  float*  pbuf = (float*)(ws + 96468992);    // dead Kc/Vtc/S region after chunks
  float*  rsum = out;                        // [16][8][2][LQ] = 1MB in d_out
  unsigned char* mkb = (unsigned char*)out + (1 << 20);  // 2MB in d_out

  const int n_w = NH * DD * DD;          // 2,097,152
  const int n_xc = LB * LQ * DD;         // 1,048,576 per chunk
  const int n_mk = LB * LQ * LK;         // 2,097,152 per chunk

  cvt_w3<<<dim3(n_w / 1024, 3), 256, 0, stream>>>(Wq, Wk, Wv, wqb, wkb, wvb, n_w);

  for (int c = 0; c < NCH; ++c) {
    const float* xc = x + (size_t)c * LB * LQ * DD;
    const float* sc = states + (size_t)c * LB * LK * DD;
    const int* mc = mask + (size_t)c * LB * LQ * LK;
    bf16_t* ctxc = ctxb + (size_t)c * LB * LQ * (NH * DD);

    cvt_pair<<<dim3(n_xc / 1024, 2), 256, 0, stream>>>(xc, xcb, sc, scb, n_xc);
    cvt_mask<<<n_mk / 1024, 256, 0, stream>>>(mc, mkb, n_mk);

    // fused Q/K/Vt projections: 1536 blocks = 6 blocks/CU
    gemm_qkv<<<dim3(32, 3 * LB * NH), 256, 0, stream>>>(
        xcb, scb, wqb, wkb, wvb, bq, bk, bv, Qc, Kc, Vtc);

    // attention as two GEMM passes
    gemm_qk<<<dim3(8, 8, LB * NH), 256, 0, stream>>>(Qc, Kc, mkb, Sb, rsum);
    gemm_pv<<<dim3(8, 4, LB * NH), 256, 0, stream>>>(Sb, Vtc, rsum, ctxc);
  }

  // out = ctx @ Wp^T + bp : split-K=4 (1024 blocks) + reduce
  cvt_f32_bf16<<<n_w / 1024, 256, 0, stream>>>(Wp, wpb, n_w);
  gemm_outk<<<dim3(64, 4, 4), 256, 0, stream>>>(ctxb, wpb, pbuf);
  reduce_out<<<(B_DIM * LQ * DD) / 1024, 256, 0, stream>>>(pbuf, bp, out);
}

// Round 4
// 530.950 us; speedup vs baseline: 1.2416x; 1.1198x over previous
//
#include <hip/hip_runtime.h>
#include <hip/hip_bf16.h>

typedef __bf16 bf16_t;
typedef __bf16 bf16x8 __attribute__((ext_vector_type(8)));
typedef float f32x4 __attribute__((ext_vector_type(4)));

#define B_DIM 8
#define LQ 1024
#define LK 1024
#define DD 512
#define NH 8
#define LB 2          // batches per chunk
#define NCH 4         // chunks

static __device__ __forceinline__ f32x4 mfma_bf16(bf16x8 a, bf16x8 b, f32x4 c) {
  return __builtin_amdgcn_mfma_f32_16x16x32_bf16(a, b, c, 0, 0, 0);
}

// async global->LDS, 16B per lane (wave-uniform LDS base + lane*16)
static __device__ __forceinline__ void gld_lds16(const bf16_t* g, bf16_t* l) {
  __builtin_amdgcn_global_load_lds(
      (const __attribute__((address_space(1))) void*)g,
      (__attribute__((address_space(3))) void*)l, 16, 0, 0);
}

// XCD-aware chunked swizzle (T1): HW assigns linear block id round-robin to
// the 8 XCDs (lin%8).  Remap so each XCD owns a CONTIGUOUS nwg/8 range of
// logical work -> blocks sharing operand panels co-reside on one XCD's L2.
// Bijective for nwg % 8 == 0 (all our grids: 1536/1024/512/1024).
static __device__ __forceinline__ int xcd_swz(int lin, int nwg) {
  return (lin & 7) * (nwg >> 3) + (lin >> 3);
}

// ---------------- fp32 -> bf16 conversions ----------------
__global__ void cvt_pair(const float* __restrict__ s0, bf16_t* __restrict__ d0,
                         const float* __restrict__ s1, bf16_t* __restrict__ d1, int n) {
  const float* s = blockIdx.y ? s1 : s0;
  bf16_t* d = blockIdx.y ? d1 : d0;
  int i = (blockIdx.x * 256 + threadIdx.x) * 4;
  if (i < n) {
    const float4 f = *(const float4*)(s + i);
    bf16_t* p = d + i;
    p[0] = (bf16_t)f.x; p[1] = (bf16_t)f.y; p[2] = (bf16_t)f.z; p[3] = (bf16_t)f.w;
  }
}

// all 4 weight matrices in one upfront dispatch (moves Wp cvt off the tail)
__global__ void cvt_w4(const float* __restrict__ s0, const float* __restrict__ s1,
                       const float* __restrict__ s2, const float* __restrict__ s3,
                       bf16_t* __restrict__ d0, bf16_t* __restrict__ d1,
                       bf16_t* __restrict__ d2, bf16_t* __restrict__ d3, int n) {
  const float* s = (blockIdx.y == 0) ? s0 : (blockIdx.y == 1) ? s1
                   : (blockIdx.y == 2) ? s2 : s3;
  bf16_t* d = (blockIdx.y == 0) ? d0 : (blockIdx.y == 1) ? d1
              : (blockIdx.y == 2) ? d2 : d3;
  int i = (blockIdx.x * 256 + threadIdx.x) * 4;
  if (i < n) {
    const float4 f = *(const float4*)(s + i);
    bf16_t* p = d + i;
    p[0] = (bf16_t)f.x; p[1] = (bf16_t)f.y; p[2] = (bf16_t)f.z; p[3] = (bf16_t)f.w;
  }
}

// mask int32 -> int8 (values 0/1), entire mask once upfront: 4x less traffic
// in gemm_qk and fewer dispatches.
__global__ void cvt_mask(const int* __restrict__ m, unsigned char* __restrict__ d, int n) {
  int i = (blockIdx.x * 256 + threadIdx.x) * 4;
  if (i < n) {
    const int4 v = *(const int4*)(m + i);
    uchar4 o;
    o.x = (unsigned char)v.x; o.y = (unsigned char)v.y;
    o.z = (unsigned char)v.z; o.w = (unsigned char)v.w;
    *(uchar4*)(d + i) = o;
  }
}

// ---------------- GEMM mainloop: BK=64, XOR-swizzled LDS ----------------
// C-tile 128x128, BK=64 (32 MFMA per barrier-pair), global_load_lds width-16.
// LDS layout: slot s in [0,1024) holds row r=s>>3, global col-chunk (s&7)^(r&7)
// (8 bf16 per chunk). global_load_lds forces dst=base+lane*16, so the swizzle
// permutes WHICH global chunk each lane fetches. Frag reads then spread the 16
// l15-lanes across all 8 bank groups -> conflict-free ds_read_b128.
static __device__ __forceinline__ void gemm_core(
    const bf16_t* __restrict__ A, const bf16_t* __restrict__ B, int ld, int klen,
    int m0, int n0, bf16_t* As, bf16_t* Bs, f32x4 (&acc)[4][4])
{
  const int tid = threadIdx.x;
  const int wave = tid >> 6, lane = tid & 63;
  const int l15 = lane & 15, quad = lane >> 4;
  const int wm = (wave & 1) * 64, wn = (wave >> 1) * 64;

  const int r0 = tid >> 3;        // + p*32 per pass
  const int c8s = tid & 7;        // stored chunk index
  bf16_t* Asl = As + tid * 8;
  bf16_t* Bsl = Bs + tid * 8;

  for (int k0 = 0; k0 < klen; k0 += 64) {
    __syncthreads();
#pragma unroll
    for (int p = 0; p < 4; ++p) {
      const int r = r0 + p * 32;
      const int gc = ((c8s ^ (r & 7)) * 8) + k0;
      gld_lds16(A + (size_t)(m0 + r) * ld + gc, Asl + p * 2048);
      gld_lds16(B + (size_t)(n0 + r) * ld + gc, Bsl + p * 2048);
    }
    __syncthreads();  // drains vmcnt
#pragma unroll
    for (int ks = 0; ks < 2; ++ks) {
      bf16x8 af[4], bfr[4];
#pragma unroll
      for (int i = 0; i < 4; ++i) {
        const int r = wm + i * 16 + l15;
        af[i] = *(const bf16x8*)&As[(r * 8 + ((ks * 4 + quad) ^ (r & 7))) * 8];
      }
#pragma unroll
      for (int j = 0; j < 4; ++j) {
        const int r = wn + j * 16 + l15;
        bfr[j] = *(const bf16x8*)&Bs[(r * 8 + ((ks * 4 + quad) ^ (r & 7))) * 8];
      }
#pragma unroll
      for (int i = 0; i < 4; ++i)
#pragma unroll
        for (int j = 0; j < 4; ++j)
          acc[i][j] = mfma_bf16(af[i], bfr[j], acc[i][j]);
    }
  }
}

// ---------------- fused Q/K/Vt projections ----------------
// grid (32, 3*LB*NH) = 1536 blocks.  Logical id from xcd_swz: each XCD owns
// 6 complete (role,z) groups (32 blocks each sharing a 2MB weight+input set).
__global__ __launch_bounds__(256, 4) void gemm_qkv(
    const bf16_t* __restrict__ xcb, const bf16_t* __restrict__ scb,
    const bf16_t* __restrict__ wq, const bf16_t* __restrict__ wk,
    const bf16_t* __restrict__ wv,
    const float* __restrict__ bq, const float* __restrict__ bk,
    const float* __restrict__ bv,
    bf16_t* __restrict__ Qc, bf16_t* __restrict__ Kc, bf16_t* __restrict__ Vtc)
{
  const int lin = blockIdx.y * 32 + blockIdx.x;
  const int wg = xcd_swz(lin, 32 * 3 * LB * NH);
  const int tx = wg & 31, yy = wg >> 5;
  const int role = yy >> 4, z = yy & 15;
  const int bb = z >> 3, hh = z & 7;

  const bf16_t* A; const bf16_t* Bm; const float* bias; bf16_t* C;
  int m0, n0, ldc, bias_row;
  if (role == 0) {
    A = xcb + (size_t)bb * LQ * DD; Bm = wq + (size_t)hh * DD * DD;
    bias = bq + hh * DD; C = Qc + (size_t)z * LQ * DD;
    m0 = (tx >> 2) * 128; n0 = (tx & 3) * 128; ldc = DD; bias_row = 0;
  } else if (role == 1) {
    A = scb + (size_t)bb * LK * DD; Bm = wk + (size_t)hh * DD * DD;
    bias = bk + hh * DD; C = Kc + (size_t)z * LK * DD;
    m0 = (tx >> 2) * 128; n0 = (tx & 3) * 128; ldc = DD; bias_row = 0;
  } else {
    A = wv + (size_t)hh * DD * DD; Bm = scb + (size_t)bb * LK * DD;
    bias = bv + hh * DD; C = Vtc + (size_t)z * DD * LK;
    m0 = (tx & 3) * 128; n0 = (tx >> 2) * 128; ldc = LK; bias_row = 1;
  }

  __shared__ __align__(16) bf16_t As[128 * 64];
  __shared__ __align__(16) bf16_t Bs[128 * 64];
  f32x4 acc[4][4];
#pragma unroll
  for (int i = 0; i < 4; ++i)
#pragma unroll
    for (int j = 0; j < 4; ++j) acc[i][j] = (f32x4){0.f, 0.f, 0.f, 0.f};

  gemm_core(A, Bm, DD, DD, m0, n0, As, Bs, acc);

  const int tid = threadIdx.x, wave = tid >> 6, lane = tid & 63;
  const int l15 = lane & 15, quad = lane >> 4;
  const int wm = (wave & 1) * 64, wn = (wave >> 1) * 64;
#pragma unroll
  for (int i = 0; i < 4; ++i)
#pragma unroll
    for (int j = 0; j < 4; ++j)
#pragma unroll
      for (int r = 0; r < 4; ++r) {
        const int row = m0 + wm + i * 16 + quad * 4 + r;
        const int col = n0 + wn + j * 16 + l15;
        const float v = acc[i][j][r] + (bias_row ? bias[row] : bias[col]);
        C[(size_t)row * ldc + col] = (bf16_t)v;
      }
}

// ---------------- pass 1: S = exp(mask ? QK^T*scale : 0), rowsum partials ----
// grid (8, 8, LB*NH) = 1024 blocks; swizzled -> each XCD owns 2 full z-groups
// (64 blocks sharing 4MB of Q/K).  rs layout: [z][ntile(8)][half(2)][LQ] f32.
__global__ __launch_bounds__(256, 4) void gemm_qk(
    const bf16_t* __restrict__ Q, const bf16_t* __restrict__ K,
    const unsigned char* __restrict__ maskb, bf16_t* __restrict__ S,
    float* __restrict__ rs)
{
  const int lin = (blockIdx.z * 8 + blockIdx.y) * 8 + blockIdx.x;
  const int wg = xcd_swz(lin, 8 * 8 * LB * NH);
  const int bx = wg & 7, nt = (wg >> 3) & 7, z = wg >> 6;
  const int bb = z >> 3;
  const bf16_t* Az = Q + (size_t)z * LQ * DD;
  const bf16_t* Bz = K + (size_t)z * LK * DD;
  bf16_t* Sz = S + (size_t)z * LQ * LK;
  const unsigned char* mz = maskb + (size_t)bb * LQ * LK;

  const int m0 = bx * 128, n0 = nt * 128;
  __shared__ __align__(16) bf16_t As[128 * 64];
  __shared__ __align__(16) bf16_t Bs[128 * 64];
  f32x4 acc[4][4];
#pragma unroll
  for (int i = 0; i < 4; ++i)
#pragma unroll
    for (int j = 0; j < 4; ++j) acc[i][j] = (f32x4){0.f, 0.f, 0.f, 0.f};

  gemm_core(Az, Bz, DD, DD, m0, n0, As, Bs, acc);

  const int tid = threadIdx.x, wave = tid >> 6, lane = tid & 63;
  const int l15 = lane & 15, quad = lane >> 4;
  const int wm = (wave & 1) * 64, wn = (wave >> 1) * 64;
  float* rsz = rs + (((size_t)z * 8 + nt) * 2 + (wave >> 1)) * LQ;
  const float scale = 0.04419417382415922f;  // 1/sqrt(512)

#pragma unroll
  for (int i = 0; i < 4; ++i)
#pragma unroll
    for (int r = 0; r < 4; ++r) {
      const int row = m0 + wm + i * 16 + quad * 4 + r;
      float rsum = 0.f;
#pragma unroll
      for (int j = 0; j < 4; ++j) {
        const int col = n0 + wn + j * 16 + l15;
        const int mv = mz[(size_t)row * LK + col];
        const float p = mv ? __expf(acc[i][j][r] * scale) : 0.f;
        rsum += p;
        Sz[(size_t)row * LK + col] = (bf16_t)p;
      }
      rsum += __shfl_xor(rsum, 1);
      rsum += __shfl_xor(rsum, 2);
      rsum += __shfl_xor(rsum, 4);
      rsum += __shfl_xor(rsum, 8);
      if (l15 == 0) rsz[row] = rsum;   // block+half-owned slot, no race
    }
}

// ---------------- pass 2: ctx = (S * inv_rowsum) . V ----------------
// grid (8, 4, LB*NH) = 512 blocks; swizzled -> each XCD owns 2 z-groups.
__global__ __launch_bounds__(256, 4) void gemm_pv(
    const bf16_t* __restrict__ S, const bf16_t* __restrict__ Vt,
    const float* __restrict__ rs, bf16_t* __restrict__ ctx)
{
  const int lin = (blockIdx.z * 4 + blockIdx.y) * 8 + blockIdx.x;
  const int wg = xcd_swz(lin, 8 * 4 * LB * NH);
  const int bx = wg & 7, by = (wg >> 3) & 3, z = wg >> 5;
  const int bb = z >> 3, hh = z & 7;
  const bf16_t* Az = S + (size_t)z * LQ * LK;
  const bf16_t* Bz = Vt + (size_t)z * DD * LK;
  bf16_t* Cz = ctx + (size_t)bb * LQ * (NH * DD) + (size_t)hh * DD;

  const int m0 = bx * 128, n0 = by * 128;
  __shared__ __align__(16) bf16_t As[128 * 64];
  __shared__ __align__(16) bf16_t Bs[128 * 64];
  __shared__ float invs[128];

  const int tid = threadIdx.x;
  if (tid < 128) {   // rowsum reduce for this block's 128 rows
    const float* p = rs + (size_t)z * 16 * LQ + (m0 + tid);
    float tot = 0.f;
#pragma unroll
    for (int s = 0; s < 16; ++s) tot += p[s * LQ];
    invs[tid] = 1.f / tot;
  }
  // visibility guaranteed by gemm_core's internal barriers before epilogue

  f32x4 acc[4][4];
#pragma unroll
  for (int i = 0; i < 4; ++i)
#pragma unroll
    for (int j = 0; j < 4; ++j) acc[i][j] = (f32x4){0.f, 0.f, 0.f, 0.f};

  gemm_core(Az, Bz, LK, LK, m0, n0, As, Bs, acc);

  const int wave = tid >> 6, lane = tid & 63;
  const int l15 = lane & 15, quad = lane >> 4;
  const int wm = (wave & 1) * 64, wn = (wave >> 1) * 64;

#pragma unroll
  for (int i = 0; i < 4; ++i)
#pragma unroll
    for (int r = 0; r < 4; ++r) {
      const int lrow = wm + i * 16 + quad * 4 + r;
      const float iv = invs[lrow];
#pragma unroll
      for (int j = 0; j < 4; ++j) {
        const int col = n0 + wn + j * 16 + l15;
        Cz[(size_t)(m0 + lrow) * (NH * DD) + col] = (bf16_t)(acc[i][j][r] * iv);
      }
    }
}

// ---------------- out-projection, split-K=4 ----------------
// grid (64, 4, 4) = 1024 blocks; swizzled -> each XCD owns 2 complete
// (n0,ks) groups (64 blocks sharing a 512KB weight panel).
__global__ __launch_bounds__(256, 4) void gemm_outk(
    const bf16_t* __restrict__ ctx, const bf16_t* __restrict__ wp,
    float* __restrict__ partial)
{
  const int lin = (blockIdx.z * 4 + blockIdx.y) * 64 + blockIdx.x;
  const int wg = xcd_swz(lin, 1024);
  const int bx = wg & 63, by = (wg >> 6) & 3, ks = wg >> 8;
  const bf16_t* A = ctx + ks * 1024;
  const bf16_t* B = wp + ks * 1024;
  float* P = partial + (size_t)ks * B_DIM * LQ * DD;

  const int m0 = bx * 128, n0 = by * 128;
  __shared__ __align__(16) bf16_t As[128 * 64];
  __shared__ __align__(16) bf16_t Bs[128 * 64];
  f32x4 acc[4][4];
#pragma unroll
  for (int i = 0; i < 4; ++i)
#pragma unroll
    for (int j = 0; j < 4; ++j) acc[i][j] = (f32x4){0.f, 0.f, 0.f, 0.f};

  gemm_core(A, B, NH * DD, 1024, m0, n0, As, Bs, acc);

  const int tid = threadIdx.x, wave = tid >> 6, lane = tid & 63;
  const int l15 = lane & 15, quad = lane >> 4;
  const int wm = (wave & 1) * 64, wn = (wave >> 1) * 64;
#pragma unroll
  for (int i = 0; i < 4; ++i)
#pragma unroll
    for (int j = 0; j < 4; ++j)
#pragma unroll
      for (int r = 0; r < 4; ++r) {
        const int row = m0 + wm + i * 16 + quad * 4 + r;
        const int col = n0 + wn + j * 16 + l15;
        P[(size_t)row * DD + col] = acc[i][j][r];
      }
}

__global__ void reduce_out(const float* __restrict__ p, const float* __restrict__ bp,
                           float* __restrict__ out) {
  const int N = B_DIM * LQ * DD;
  int i = (blockIdx.x * 256 + threadIdx.x) * 4;
  float4 a = *(const float4*)(p + i);
  float4 b = *(const float4*)(p + N + i);
  float4 c = *(const float4*)(p + 2 * N + i);
  float4 d = *(const float4*)(p + 3 * N + i);
  const float4 bb4 = *(const float4*)(bp + (i & 511));
  float4 r;
  r.x = a.x + b.x + c.x + d.x + bb4.x;
  r.y = a.y + b.y + c.y + d.y + bb4.y;
  r.z = a.z + b.z + c.z + d.z + bb4.z;
  r.w = a.w + b.w + c.w + d.w + bb4.w;
  *(float4*)(out + i) = r;
}

// ---------------- host launcher ----------------
extern "C" void kernel_launch(void* const* d_in, const int* in_sizes, int n_in,
                              void* d_out, int out_size, void* d_ws, size_t ws_size,
                              hipStream_t stream) {
  const float* x      = (const float*)d_in[0];
  const float* states = (const float*)d_in[1];
  const int*   mask   = (const int*)d_in[2];
  const float* Wq     = (const float*)d_in[3];
  const float* bq     = (const float*)d_in[4];
  const float* Wk     = (const float*)d_in[5];
  const float* bk     = (const float*)d_in[6];
  const float* Wv     = (const float*)d_in[7];
  const float* bv     = (const float*)d_in[8];
  const float* Wp     = (const float*)d_in[9];
  const float* bp     = (const float*)d_in[10];
  float* out = (float*)d_out;

  // Workspace layout (ends at exactly 167,772,160 B = 160 MiB, proven safe):
  //   ctx 64MB @ 0 ; wqb/wkb/wvb 4MB each @ 64M..76M
  //   Qc 16MB @ 76M ; Kc 16MB @ 92M ; Vtc 16MB @ 108M
  //   S 32MB @ 124M ; xcb 2MB @ 156M ; scb 2MB @ 158M
  //   out-proj fp32 partials (64MB) reuse Kc/Vtc/S after chunks
  // d_out (16MB) scratch until reduce_out overwrites it:
  //   rowsum partials 1MB @ 0 ; mask-int8 (all chunks) 8MB @ 1M ; wpb 4MB @ 9M
  char* ws = (char*)d_ws;
  bf16_t* ctxb = (bf16_t*)(ws + 0);
  bf16_t* wqb  = (bf16_t*)(ws + 67108864);
  bf16_t* wkb  = (bf16_t*)(ws + 71303168);
  bf16_t* wvb  = (bf16_t*)(ws + 75497472);
  bf16_t* Qc   = (bf16_t*)(ws + 79691776);
  bf16_t* Kc   = (bf16_t*)(ws + 96468992);
  bf16_t* Vtc  = (bf16_t*)(ws + 113246208);
  bf16_t* Sb   = (bf16_t*)(ws + 130023424);
  bf16_t* xcb  = (bf16_t*)(ws + 163577856);
  bf16_t* scb  = (bf16_t*)(ws + 165675008);
  float*  pbuf = (float*)(ws + 96468992);    // dead Kc/Vtc/S region after chunks
  float*  rsum = out;                                     // 1MB @ d_out+0
  unsigned char* mkb = (unsigned char*)out + (1 << 20);   // 8MB @ d_out+1M
  bf16_t* wpb  = (bf16_t*)((char*)out + 9 * (1 << 20));   // 4MB @ d_out+9M

  const int n_w = NH * DD * DD;          // 2,097,152 (all four weights equal)
  const int n_xc = LB * LQ * DD;         // 1,048,576 per chunk
  const int n_mk_all = B_DIM * LQ * LK;  // 8,388,608 (whole mask)

  // upfront: all weights (incl. Wp -> d_out scratch) + whole mask to int8
  cvt_w4<<<dim3(n_w / 1024, 4), 256, 0, stream>>>(
      Wq, Wk, Wv, Wp, wqb, wkb, wvb, wpb, n_w);
  cvt_mask<<<n_mk_all / 1024, 256, 0, stream>>>(mask, mkb, n_mk_all);

  for (int c = 0; c < NCH; ++c) {
    const float* xc = x + (size_t)c * LB * LQ * DD;
    const float* sc = states + (size_t)c * LB * LK * DD;
    const unsigned char* mc = mkb + (size_t)c * LB * LQ * LK;
    bf16_t* ctxc = ctxb + (size_t)c * LB * LQ * (NH * DD);

    cvt_pair<<<dim3(n_xc / 1024, 2), 256, 0, stream>>>(xc, xcb, sc, scb, n_xc);

    // fused Q/K/Vt projections: 1536 blocks = 6 blocks/CU
    gemm_qkv<<<dim3(32, 3 * LB * NH), 256, 0, stream>>>(
        xcb, scb, wqb, wkb, wvb, bq, bk, bv, Qc, Kc, Vtc);

    // attention as two GEMM passes
    gemm_qk<<<dim3(8, 8, LB * NH), 256, 0, stream>>>(Qc, Kc, mc, Sb, rsum);
    gemm_pv<<<dim3(8, 4, LB * NH), 256, 0, stream>>>(Sb, Vtc, rsum, ctxc);
  }

  // out = ctx @ Wp^T + bp : split-K=4 (1024 blocks) + reduce
  gemm_outk<<<dim3(64, 4, 4), 256, 0, stream>>>(ctxb, wpb, pbuf);
  reduce_out<<<(B_DIM * LQ * DD) / 1024, 256, 0, stream>>>(pbuf, bp, out);
}

// Round 5
// 501.311 us; speedup vs baseline: 1.3150x; 1.0591x over previous
//
#include <hip/hip_runtime.h>
#include <hip/hip_bf16.h>

typedef __bf16 bf16_t;
typedef __bf16 bf16x8 __attribute__((ext_vector_type(8)));
typedef float f32x4 __attribute__((ext_vector_type(4)));

#define B_DIM 8
#define LQ 1024
#define LK 1024
#define DD 512
#define NH 8
#define LB 2          // batches per chunk
#define NCH 4         // chunks

static __device__ __forceinline__ f32x4 mfma_bf16(bf16x8 a, bf16x8 b, f32x4 c) {
  return __builtin_amdgcn_mfma_f32_16x16x32_bf16(a, b, c, 0, 0, 0);
}

// async global->LDS, 16B per lane (wave-uniform LDS base + lane*16)
static __device__ __forceinline__ void gld_lds16(const bf16_t* g, bf16_t* l) {
  __builtin_amdgcn_global_load_lds(
      (const __attribute__((address_space(1))) void*)g,
      (__attribute__((address_space(3))) void*)l, 16, 0, 0);
}

// XCD-aware chunked swizzle (T1): HW assigns linear block id round-robin to
// the 8 XCDs (lin%8).  Remap so each XCD owns a CONTIGUOUS nwg/8 range of
// logical work -> blocks sharing operand panels co-reside on one XCD's L2.
// NOT applied to gemm_outk: its natural mapping already co-locates the 4
// A-strip siblings (lin stride 64) on one XCD; chunked swizzle scattered
// them and doubled FETCH_SIZE (52->119MB, R4 counters).
static __device__ __forceinline__ int xcd_swz(int lin, int nwg) {
  return (lin & 7) * (nwg >> 3) + (lin >> 3);
}

// ---------------- one upfront conversion kernel ----------------
// Flattened 1D grid over float4/int4 groups:
//   [0, 2M)      : 4 weight matrices fp32->bf16 (512K groups each)
//   [2M, 4M)     : x then states fp32->bf16 (1M groups each)
//   [4M, 6M)     : mask int32->int8 (2M groups)
// Replaces cvt_w4 + cvt_mask + 4x cvt_pair (5 dispatches + gaps).
__global__ void cvt_all(
    const float* __restrict__ Wq, const float* __restrict__ Wk,
    const float* __restrict__ Wv, const float* __restrict__ Wp,
    const float* __restrict__ x, const float* __restrict__ st,
    const int* __restrict__ mask,
    bf16_t* __restrict__ wqb, bf16_t* __restrict__ wkb,
    bf16_t* __restrict__ wvb, bf16_t* __restrict__ wpb,
    bf16_t* __restrict__ xb, bf16_t* __restrict__ sb,
    unsigned char* __restrict__ mkb)
{
  const int g = blockIdx.x * 256 + threadIdx.x;
  if (g < 2097152) {                       // weights
    const int w = g >> 19;
    const int i = (g & 524287) * 4;
    const float* s4 = (w == 0) ? Wq : (w == 1) ? Wk : (w == 2) ? Wv : Wp;
    bf16_t* d = (w == 0) ? wqb : (w == 1) ? wkb : (w == 2) ? wvb : wpb;
    const float4 f = *(const float4*)(s4 + i);
    bf16_t* p = d + i;
    p[0] = (bf16_t)f.x; p[1] = (bf16_t)f.y; p[2] = (bf16_t)f.z; p[3] = (bf16_t)f.w;
  } else if (g < 4194304) {                // x / states
    const int h = g - 2097152;
    const int i = (h & 1048575) * 4;
    const float* s4 = (h >> 20) ? st : x;
    bf16_t* d = (h >> 20) ? sb : xb;
    const float4 f = *(const float4*)(s4 + i);
    bf16_t* p = d + i;
    p[0] = (bf16_t)f.x; p[1] = (bf16_t)f.y; p[2] = (bf16_t)f.z; p[3] = (bf16_t)f.w;
  } else {                                 // mask
    const int i = (g - 4194304) * 4;
    const int4 v = *(const int4*)(mask + i);
    uchar4 o;
    o.x = (unsigned char)v.x; o.y = (unsigned char)v.y;
    o.z = (unsigned char)v.z; o.w = (unsigned char)v.w;
    *(uchar4*)(mkb + i) = o;
  }
}

// ---------------- GEMM mainloop: BK=64, XOR-swizzled LDS ----------------
// C-tile 128x128, BK=64 (32 MFMA per barrier-pair), global_load_lds width-16.
// LDS layout: slot s in [0,1024) holds row r=s>>3, global col-chunk (s&7)^(r&7)
// (8 bf16 per chunk). global_load_lds forces dst=base+lane*16, so the swizzle
// permutes WHICH global chunk each lane fetches. Frag reads then spread the 16
// l15-lanes across all 8 bank groups -> conflict-free ds_read_b128.
static __device__ __forceinline__ void gemm_core(
    const bf16_t* __restrict__ A, const bf16_t* __restrict__ B, int ld, int klen,
    int m0, int n0, bf16_t* As, bf16_t* Bs, f32x4 (&acc)[4][4])
{
  const int tid = threadIdx.x;
  const int wave = tid >> 6, lane = tid & 63;
  const int l15 = lane & 15, quad = lane >> 4;
  const int wm = (wave & 1) * 64, wn = (wave >> 1) * 64;

  const int r0 = tid >> 3;        // + p*32 per pass
  const int c8s = tid & 7;        // stored chunk index
  bf16_t* Asl = As + tid * 8;
  bf16_t* Bsl = Bs + tid * 8;

  for (int k0 = 0; k0 < klen; k0 += 64) {
    __syncthreads();
#pragma unroll
    for (int p = 0; p < 4; ++p) {
      const int r = r0 + p * 32;
      const int gc = ((c8s ^ (r & 7)) * 8) + k0;
      gld_lds16(A + (size_t)(m0 + r) * ld + gc, Asl + p * 2048);
      gld_lds16(B + (size_t)(n0 + r) * ld + gc, Bsl + p * 2048);
    }
    __syncthreads();  // drains vmcnt
#pragma unroll
    for (int ks = 0; ks < 2; ++ks) {
      bf16x8 af[4], bfr[4];
#pragma unroll
      for (int i = 0; i < 4; ++i) {
        const int r = wm + i * 16 + l15;
        af[i] = *(const bf16x8*)&As[(r * 8 + ((ks * 4 + quad) ^ (r & 7))) * 8];
      }
#pragma unroll
      for (int j = 0; j < 4; ++j) {
        const int r = wn + j * 16 + l15;
        bfr[j] = *(const bf16x8*)&Bs[(r * 8 + ((ks * 4 + quad) ^ (r & 7))) * 8];
      }
#pragma unroll
      for (int i = 0; i < 4; ++i)
#pragma unroll
        for (int j = 0; j < 4; ++j)
          acc[i][j] = mfma_bf16(af[i], bfr[j], acc[i][j]);
    }
  }
}

// ---------------- fused Q/K/Vt projections ----------------
// grid (32, 3*LB*NH) = 1536 blocks.  Logical id from xcd_swz: each XCD owns
// 6 complete (role,z) groups (32 blocks each sharing a 2MB weight+input set).
__global__ __launch_bounds__(256, 4) void gemm_qkv(
    const bf16_t* __restrict__ xcb, const bf16_t* __restrict__ scb,
    const bf16_t* __restrict__ wq, const bf16_t* __restrict__ wk,
    const bf16_t* __restrict__ wv,
    const float* __restrict__ bq, const float* __restrict__ bk,
    const float* __restrict__ bv,
    bf16_t* __restrict__ Qc, bf16_t* __restrict__ Kc, bf16_t* __restrict__ Vtc)
{
  const int lin = blockIdx.y * 32 + blockIdx.x;
  const int wg = xcd_swz(lin, 32 * 3 * LB * NH);
  const int tx = wg & 31, yy = wg >> 5;
  const int role = yy >> 4, z = yy & 15;
  const int bb = z >> 3, hh = z & 7;

  const bf16_t* A; const bf16_t* Bm; const float* bias; bf16_t* C;
  int m0, n0, ldc, bias_row;
  if (role == 0) {
    A = xcb + (size_t)bb * LQ * DD; Bm = wq + (size_t)hh * DD * DD;
    bias = bq + hh * DD; C = Qc + (size_t)z * LQ * DD;
    m0 = (tx >> 2) * 128; n0 = (tx & 3) * 128; ldc = DD; bias_row = 0;
  } else if (role == 1) {
    A = scb + (size_t)bb * LK * DD; Bm = wk + (size_t)hh * DD * DD;
    bias = bk + hh * DD; C = Kc + (size_t)z * LK * DD;
    m0 = (tx >> 2) * 128; n0 = (tx & 3) * 128; ldc = DD; bias_row = 0;
  } else {
    A = wv + (size_t)hh * DD * DD; Bm = scb + (size_t)bb * LK * DD;
    bias = bv + hh * DD; C = Vtc + (size_t)z * DD * LK;
    m0 = (tx & 3) * 128; n0 = (tx >> 2) * 128; ldc = LK; bias_row = 1;
  }

  __shared__ __align__(16) bf16_t As[128 * 64];
  __shared__ __align__(16) bf16_t Bs[128 * 64];
  f32x4 acc[4][4];
#pragma unroll
  for (int i = 0; i < 4; ++i)
#pragma unroll
    for (int j = 0; j < 4; ++j) acc[i][j] = (f32x4){0.f, 0.f, 0.f, 0.f};

  gemm_core(A, Bm, DD, DD, m0, n0, As, Bs, acc);

  const int tid = threadIdx.x, wave = tid >> 6, lane = tid & 63;
  const int l15 = lane & 15, quad = lane >> 4;
  const int wm = (wave & 1) * 64, wn = (wave >> 1) * 64;
#pragma unroll
  for (int i = 0; i < 4; ++i)
#pragma unroll
    for (int j = 0; j < 4; ++j)
#pragma unroll
      for (int r = 0; r < 4; ++r) {
        const int row = m0 + wm + i * 16 + quad * 4 + r;
        const int col = n0 + wn + j * 16 + l15;
        const float v = acc[i][j][r] + (bias_row ? bias[row] : bias[col]);
        C[(size_t)row * ldc + col] = (bf16_t)v;
      }
}

// ---------------- pass 1: S = exp(mask ? QK^T*scale : 0), rowsum partials ----
// grid (8, 8, LB*NH) = 1024 blocks; swizzled -> each XCD owns 2 full z-groups
// (64 blocks sharing 4MB of Q/K).  rs layout: [z][ntile(8)][half(2)][LQ] f32.
__global__ __launch_bounds__(256, 4) void gemm_qk(
    const bf16_t* __restrict__ Q, const bf16_t* __restrict__ K,
    const unsigned char* __restrict__ maskb, bf16_t* __restrict__ S,
    float* __restrict__ rs)
{
  const int lin = (blockIdx.z * 8 + blockIdx.y) * 8 + blockIdx.x;
  const int wg = xcd_swz(lin, 8 * 8 * LB * NH);
  const int bx = wg & 7, nt = (wg >> 3) & 7, z = wg >> 6;
  const int bb = z >> 3;
  const bf16_t* Az = Q + (size_t)z * LQ * DD;
  const bf16_t* Bz = K + (size_t)z * LK * DD;
  bf16_t* Sz = S + (size_t)z * LQ * LK;
  const unsigned char* mz = maskb + (size_t)bb * LQ * LK;

  const int m0 = bx * 128, n0 = nt * 128;
  __shared__ __align__(16) bf16_t As[128 * 64];
  __shared__ __align__(16) bf16_t Bs[128 * 64];
  f32x4 acc[4][4];
#pragma unroll
  for (int i = 0; i < 4; ++i)
#pragma unroll
    for (int j = 0; j < 4; ++j) acc[i][j] = (f32x4){0.f, 0.f, 0.f, 0.f};

  gemm_core(Az, Bz, DD, DD, m0, n0, As, Bs, acc);

  const int tid = threadIdx.x, wave = tid >> 6, lane = tid & 63;
  const int l15 = lane & 15, quad = lane >> 4;
  const int wm = (wave & 1) * 64, wn = (wave >> 1) * 64;
  float* rsz = rs + (((size_t)z * 8 + nt) * 2 + (wave >> 1)) * LQ;
  const float scale = 0.04419417382415922f;  // 1/sqrt(512)

#pragma unroll
  for (int i = 0; i < 4; ++i)
#pragma unroll
    for (int r = 0; r < 4; ++r) {
      const int row = m0 + wm + i * 16 + quad * 4 + r;
      float rsum = 0.f;
#pragma unroll
      for (int j = 0; j < 4; ++j) {
        const int col = n0 + wn + j * 16 + l15;
        const int mv = mz[(size_t)row * LK + col];
        const float p = mv ? __expf(acc[i][j][r] * scale) : 0.f;
        rsum += p;
        Sz[(size_t)row * LK + col] = (bf16_t)p;
      }
      rsum += __shfl_xor(rsum, 1);
      rsum += __shfl_xor(rsum, 2);
      rsum += __shfl_xor(rsum, 4);
      rsum += __shfl_xor(rsum, 8);
      if (l15 == 0) rsz[row] = rsum;   // block+half-owned slot, no race
    }
}

// ---------------- pass 2: ctx = (S * inv_rowsum) . V ----------------
// grid (8, 4, LB*NH) = 512 blocks; swizzled -> each XCD owns 2 z-groups.
__global__ __launch_bounds__(256, 4) void gemm_pv(
    const bf16_t* __restrict__ S, const bf16_t* __restrict__ Vt,
    const float* __restrict__ rs, bf16_t* __restrict__ ctx)
{
  const int lin = (blockIdx.z * 4 + blockIdx.y) * 8 + blockIdx.x;
  const int wg = xcd_swz(lin, 8 * 4 * LB * NH);
  const int bx = wg & 7, by = (wg >> 3) & 3, z = wg >> 5;
  const int bb = z >> 3, hh = z & 7;
  const bf16_t* Az = S + (size_t)z * LQ * LK;
  const bf16_t* Bz = Vt + (size_t)z * DD * LK;
  bf16_t* Cz = ctx + (size_t)bb * LQ * (NH * DD) + (size_t)hh * DD;

  const int m0 = bx * 128, n0 = by * 128;
  __shared__ __align__(16) bf16_t As[128 * 64];
  __shared__ __align__(16) bf16_t Bs[128 * 64];
  __shared__ float invs[128];

  const int tid = threadIdx.x;
  if (tid < 128) {   // rowsum reduce for this block's 128 rows
    const float* p = rs + (size_t)z * 16 * LQ + (m0 + tid);
    float tot = 0.f;
#pragma unroll
    for (int s = 0; s < 16; ++s) tot += p[s * LQ];
    invs[tid] = 1.f / tot;
  }
  // visibility guaranteed by gemm_core's internal barriers before epilogue

  f32x4 acc[4][4];
#pragma unroll
  for (int i = 0; i < 4; ++i)
#pragma unroll
    for (int j = 0; j < 4; ++j) acc[i][j] = (f32x4){0.f, 0.f, 0.f, 0.f};

  gemm_core(Az, Bz, LK, LK, m0, n0, As, Bs, acc);

  const int wave = tid >> 6, lane = tid & 63;
  const int l15 = lane & 15, quad = lane >> 4;
  const int wm = (wave & 1) * 64, wn = (wave >> 1) * 64;

#pragma unroll
  for (int i = 0; i < 4; ++i)
#pragma unroll
    for (int r = 0; r < 4; ++r) {
      const int lrow = wm + i * 16 + quad * 4 + r;
      const float iv = invs[lrow];
#pragma unroll
      for (int j = 0; j < 4; ++j) {
        const int col = n0 + wn + j * 16 + l15;
        Cz[(size_t)(m0 + lrow) * (NH * DD) + col] = (bf16_t)(acc[i][j][r] * iv);
      }
    }
}

// ---------------- out-projection, split-K=4 ----------------
// grid (64, 4, 4) = 1024 blocks, NATURAL mapping: the 4 by-siblings sharing
// an A-strip sit at lin stride 64 -> same XCD for free (R4 swizzle broke
// this: FETCH 52->119MB).
__global__ __launch_bounds__(256, 4) void gemm_outk(
    const bf16_t* __restrict__ ctx, const bf16_t* __restrict__ wp,
    float* __restrict__ partial)
{
  const int ks = blockIdx.z;
  const bf16_t* A = ctx + ks * 1024;
  const bf16_t* B = wp + ks * 1024;
  float* P = partial + (size_t)ks * B_DIM * LQ * DD;

  const int m0 = blockIdx.x * 128, n0 = blockIdx.y * 128;
  __shared__ __align__(16) bf16_t As[128 * 64];
  __shared__ __align__(16) bf16_t Bs[128 * 64];
  f32x4 acc[4][4];
#pragma unroll
  for (int i = 0; i < 4; ++i)
#pragma unroll
    for (int j = 0; j < 4; ++j) acc[i][j] = (f32x4){0.f, 0.f, 0.f, 0.f};

  gemm_core(A, B, NH * DD, 1024, m0, n0, As, Bs, acc);

  const int tid = threadIdx.x, wave = tid >> 6, lane = tid & 63;
  const int l15 = lane & 15, quad = lane >> 4;
  const int wm = (wave & 1) * 64, wn = (wave >> 1) * 64;
#pragma unroll
  for (int i = 0; i < 4; ++i)
#pragma unroll
    for (int j = 0; j < 4; ++j)
#pragma unroll
      for (int r = 0; r < 4; ++r) {
        const int row = m0 + wm + i * 16 + quad * 4 + r;
        const int col = n0 + wn + j * 16 + l15;
        P[(size_t)row * DD + col] = acc[i][j][r];
      }
}

__global__ void reduce_out(const float* __restrict__ p, const float* __restrict__ bp,
                           float* __restrict__ out) {
  const int N = B_DIM * LQ * DD;
  int i = (blockIdx.x * 256 + threadIdx.x) * 4;
  float4 a = *(const float4*)(p + i);
  float4 b = *(const float4*)(p + N + i);
  float4 c = *(const float4*)(p + 2 * N + i);
  float4 d = *(const float4*)(p + 3 * N + i);
  const float4 bb4 = *(const float4*)(bp + (i & 511));
  float4 r;
  r.x = a.x + b.x + c.x + d.x + bb4.x;
  r.y = a.y + b.y + c.y + d.y + bb4.y;
  r.z = a.z + b.z + c.z + d.z + bb4.z;
  r.w = a.w + b.w + c.w + d.w + bb4.w;
  *(float4*)(out + i) = r;
}

// ---------------- host launcher ----------------
extern "C" void kernel_launch(void* const* d_in, const int* in_sizes, int n_in,
                              void* d_out, int out_size, void* d_ws, size_t ws_size,
                              hipStream_t stream) {
  const float* x      = (const float*)d_in[0];
  const float* states = (const float*)d_in[1];
  const int*   mask   = (const int*)d_in[2];
  const float* Wq     = (const float*)d_in[3];
  const float* bq     = (const float*)d_in[4];
  const float* Wk     = (const float*)d_in[5];
  const float* bk     = (const float*)d_in[6];
  const float* Wv     = (const float*)d_in[7];
  const float* bv     = (const float*)d_in[8];
  const float* Wp     = (const float*)d_in[9];
  const float* bp     = (const float*)d_in[10];
  float* out = (float*)d_out;

  // Workspace layout (ends at exactly 167,772,160 B = 160 MiB):
  //   ctx 64MB @ 0 ; wqb/wkb/wvb 4MB each @ 64M..76M
  //   Qc 16MB @ 76M ; Kc 16MB @ 92M ; Vtc 16MB @ 108M
  //   S 32MB @ 124M ; (156M..160M now unused)
  //   full bf16 x (8MB @ ctx+48M) and states (8MB @ ctx+56M) OVERLAY the
  //     ctx chunk-3 region: written by cvt_all upfront, last read by
  //     gemm_qkv(chunk 3), which precedes pv(3)'s write of that region
  //     in stream order.  pv(0..2) write ctx 0..48M only.
  //   out-proj fp32 partials (64MB) reuse Kc/Vtc/S after chunks
  // d_out (16MB) scratch until reduce_out overwrites it:
  //   rowsum partials 1MB @ 0 ; mask-int8 8MB @ 1M ; wpb 4MB @ 9M
  char* ws = (char*)d_ws;
  bf16_t* ctxb = (bf16_t*)(ws + 0);
  bf16_t* xbF  = (bf16_t*)(ws + 50331648);   // 48 MiB
  bf16_t* sbF  = (bf16_t*)(ws + 58720256);   // 56 MiB
  bf16_t* wqb  = (bf16_t*)(ws + 67108864);
  bf16_t* wkb  = (bf16_t*)(ws + 71303168);
  bf16_t* wvb  = (bf16_t*)(ws + 75497472);
  bf16_t* Qc   = (bf16_t*)(ws + 79691776);
  bf16_t* Kc   = (bf16_t*)(ws + 96468992);
  bf16_t* Vtc  = (bf16_t*)(ws + 113246208);
  bf16_t* Sb   = (bf16_t*)(ws + 130023424);
  float*  pbuf = (float*)(ws + 96468992);    // dead Kc/Vtc/S region after chunks
  float*  rsum = out;                                     // 1MB @ d_out+0
  unsigned char* mkb = (unsigned char*)out + (1 << 20);   // 8MB @ d_out+1M
  bf16_t* wpb  = (bf16_t*)((char*)out + 9 * (1 << 20));   // 4MB @ d_out+9M

  const int n_xc = LB * LQ * DD;         // 1,048,576 elements per chunk

  // one upfront conversion dispatch: 6,291,456 groups -> 24576 blocks
  cvt_all<<<24576, 256, 0, stream>>>(Wq, Wk, Wv, Wp, x, states, mask,
                                     wqb, wkb, wvb, wpb, xbF, sbF, mkb);

  for (int c = 0; c < NCH; ++c) {
    const bf16_t* xc = xbF + (size_t)c * n_xc;
    const bf16_t* sc = sbF + (size_t)c * n_xc;
    const unsigned char* mc = mkb + (size_t)c * LB * LQ * LK;
    bf16_t* ctxc = ctxb + (size_t)c * LB * LQ * (NH * DD);

    // fused Q/K/Vt projections: 1536 blocks = 6 blocks/CU
    gemm_qkv<<<dim3(32, 3 * LB * NH), 256, 0, stream>>>(
        xc, sc, wqb, wkb, wvb, bq, bk, bv, Qc, Kc, Vtc);

    // attention as two GEMM passes
    gemm_qk<<<dim3(8, 8, LB * NH), 256, 0, stream>>>(Qc, Kc, mc, Sb, rsum);
    gemm_pv<<<dim3(8, 4, LB * NH), 256, 0, stream>>>(Sb, Vtc, rsum, ctxc);
  }

  // out = ctx @ Wp^T + bp : split-K=4 (1024 blocks) + reduce
  gemm_outk<<<dim3(64, 4, 4), 256, 0, stream>>>(ctxb, wpb, pbuf);
  reduce_out<<<(B_DIM * LQ * DD) / 1024, 256, 0, stream>>>(pbuf, bp, out);
}